// Round 10
// baseline (357.758 us; speedup 1.0000x reference)
//
#include <hip/hip_runtime.h>
#include <hip/hip_bf16.h>
#include <math.h>

// RaffelAttention round 10.
// Fragment-major LDS layouts everywhere (ds_read = base + lane*16, zero bank
// conflicts, zero addr VALU). X pre-cast to bf16 -> proj BK=64. out BK=64.
// attn sync structure identical to r9 (verified); only LDS addressing changed.

#define Bc 2
#define Lc 2048
#define Dc 1024
#define Hc 16
#define Mc (Bc*Lc)
#define NT 32

typedef __attribute__((ext_vector_type(8))) __bf16 bf16x8;
typedef __attribute__((ext_vector_type(4))) float f32x4;
typedef __attribute__((ext_vector_type(16))) float f32x16;
typedef __attribute__((ext_vector_type(2))) unsigned u32x2;

union U4 { unsigned u[4]; bf16x8 v; };

__device__ __forceinline__ void gl_lds16(const void* g, void* l) {
    __builtin_amdgcn_global_load_lds(
        (const __attribute__((address_space(1))) void*)g,
        (__attribute__((address_space(3))) void*)l, 16, 0, 0);
}
__device__ __forceinline__ unsigned pkbf(float a, float b) {
    unsigned short ua = __builtin_bit_cast(unsigned short, (__bf16)a);
    unsigned short ub = __builtin_bit_cast(unsigned short, (__bf16)b);
    return (unsigned)ua | ((unsigned)ub << 16);
}
__device__ __forceinline__ float lo2f(unsigned u){ return __builtin_bit_cast(float, u << 16); }
__device__ __forceinline__ float hi2f(unsigned u){ return __builtin_bit_cast(float, u & 0xffff0000u); }
#define E2(x) __builtin_amdgcn_exp2f(x)

#define WAIT_VM0  asm volatile("s_waitcnt vmcnt(0)" ::: "memory")
#define WAIT_VM4  asm volatile("s_waitcnt vmcnt(4)" ::: "memory")
#define WAIT_VM8  asm volatile("s_waitcnt vmcnt(8)" ::: "memory")
#define WAIT_VM12 asm volatile("s_waitcnt vmcnt(12)" ::: "memory")
#define WAIT_LG0  asm volatile("s_waitcnt lgkmcnt(0)" ::: "memory")
#define SBAR __builtin_amdgcn_sched_barrier(0)
#define BARRIER do { __builtin_amdgcn_sched_barrier(0); __builtin_amdgcn_s_barrier(); __builtin_amdgcn_sched_barrier(0); } while (0)

// ---------------------------------------------------------------------------
// prep: z=0..3 Wt[z] bf16 [n][k]; z=4 Woh/Wol; z=5,6 cast hidden/pos to bf16.
// ---------------------------------------------------------------------------
__global__ __launch_bounds__(256) void prep_kernel(
    const float* __restrict__ hidden, const float* __restrict__ pos,
    const float* __restrict__ Wcq, const float* __restrict__ Wck,
    const float* __restrict__ Wpq, const float* __restrict__ Wpk,
    const float* __restrict__ Wo,
    __bf16* __restrict__ Wt, __bf16* __restrict__ Woh, __bf16* __restrict__ Wol,
    __bf16* __restrict__ Xh, __bf16* __restrict__ Xp)
{
    const int z = blockIdx.z;
    const int t = threadIdx.x;
    if (z >= 5) {   // straight cast, 32768 threads x 128 elems
        const float* X = (z==5) ? hidden : pos;
        __bf16* dst    = (z==5) ? Xh : Xp;
        const size_t base = ((size_t)(blockIdx.y*16 + blockIdx.x)*256 + t) * 128;
        #pragma unroll
        for (int c = 0; c < 16; ++c) {
            const float* sp = X + base + c*8;
            float4 v0 = *(const float4*)sp;
            float4 v1 = *(const float4*)(sp + 4);
            bf16x8 o;
            o[0]=(__bf16)v0.x; o[1]=(__bf16)v0.y; o[2]=(__bf16)v0.z; o[3]=(__bf16)v0.w;
            o[4]=(__bf16)v1.x; o[5]=(__bf16)v1.y; o[6]=(__bf16)v1.z; o[7]=(__bf16)v1.w;
            *(bf16x8*)(dst + base + c*8) = o;
        }
        return;
    }
    const float* W = (z==0)?Wcq:(z==1)?Wck:(z==2)?Wpq:(z==3)?Wpk:Wo;
    const int n  = blockIdx.x*64 + (t & 63);
    const int k0 = blockIdx.y*128 + (t >> 6)*32;
    float v[32];
    #pragma unroll
    for (int j = 0; j < 32; ++j) v[j] = W[(size_t)(k0+j)*Dc + n];
    if (z < 4) {
        __bf16* dst = Wt + (size_t)z*Dc*Dc + (size_t)n*Dc + k0;
        #pragma unroll
        for (int c = 0; c < 4; ++c) {
            bf16x8 o;
            #pragma unroll
            for (int j = 0; j < 8; ++j) o[j] = (__bf16)v[c*8+j];
            *(bf16x8*)(dst + c*8) = o;
        }
    } else {
        __bf16* dh = Woh + (size_t)n*Dc + k0;
        __bf16* dl = Wol + (size_t)n*Dc + k0;
        #pragma unroll
        for (int c = 0; c < 4; ++c) {
            bf16x8 oh, ol;
            #pragma unroll
            for (int j = 0; j < 8; ++j) {
                float x = v[c*8+j];
                __bf16 hi = (__bf16)x;
                oh[j] = hi; ol[j] = (__bf16)(x - (float)hi);
            }
            *(bf16x8*)(dh + c*8) = oh;
            *(bf16x8*)(dl + c*8) = ol;
        }
    }
}

// ---------------------------------------------------------------------------
// proj: X(bf16) @ Wt[z] -> Q'/K'. BK=64, fragment-major LDS (conflict-free).
// chunk d = h*8 + i*2 + kk; lane -> (row h*64+i*16+(lane&15), k kk*32+(lane>>4)*8)
// ---------------------------------------------------------------------------
__global__ __launch_bounds__(256) void proj_kernel(
    const __bf16* __restrict__ Xh, const __bf16* __restrict__ Xp,
    const __bf16* __restrict__ Wt,
    const float* __restrict__ bcq, const float* __restrict__ bck,
    const float* __restrict__ bpq, const float* __restrict__ bpk,
    __bf16* __restrict__ Qc, __bf16* __restrict__ Kc)
{
    const int g = blockIdx.x;
    const int nblk = g >> 7, sg = g & 127, mblk = sg & 31, z = sg >> 5;
    const int m0 = mblk*128, n0 = nblk*128;
    const __bf16* X = (z < 2) ? Xh : Xp;
    const __bf16* Wz = Wt + (size_t)z*Dc*Dc;
    const float* bias = (z==0)?bcq:(z==1)?bck:(z==2)?bpq:bpk;
    __bf16* dst = (z & 1) ? Kc : Qc;
    const int half = z >> 1;
    const float scale = (z & 1) ? 1.0f : 0.18033688011112042f; // 0.125*log2e on Q

    const int t = threadIdx.x, lane = t & 63, w = t >> 6;
    const int wm = w >> 1, wn = w & 1;

    __shared__ __align__(16) char smem[32768];   // A @0 (16KB), B @16384

    f32x4 acc[4][4] = {};

    for (int k0 = 0; k0 < Dc; k0 += 64) {
        #pragma unroll
        for (int c = 0; c < 4; ++c) {
            const int d = w*4 + c;
            const int h = d >> 3, i = (d >> 1) & 3, kk = d & 1;
            const int rr = h*64 + i*16 + (lane & 15);
            const int kc = k0 + kk*32 + (lane >> 4)*8;
            gl_lds16(X  + (size_t)(m0 + rr)*Dc + kc, smem + d*1024);
            gl_lds16(Wz + (size_t)(n0 + rr)*Dc + kc, smem + 16384 + d*1024);
        }
        WAIT_VM0; __syncthreads();
        bf16x8 a[4][2], b[4][2];
        #pragma unroll
        for (int i = 0; i < 4; ++i)
            #pragma unroll
            for (int kk = 0; kk < 2; ++kk) {
                a[i][kk] = *(const bf16x8*)(smem + (wm*8 + i*2 + kk)*1024 + lane*16);
                b[i][kk] = *(const bf16x8*)(smem + 16384 + (wn*8 + i*2 + kk)*1024 + lane*16);
            }
        #pragma unroll
        for (int mi = 0; mi < 4; ++mi)
            #pragma unroll
            for (int ni = 0; ni < 4; ++ni) {
                acc[mi][ni] = __builtin_amdgcn_mfma_f32_16x16x32_bf16(a[mi][0], b[ni][0], acc[mi][ni], 0, 0, 0);
                acc[mi][ni] = __builtin_amdgcn_mfma_f32_16x16x32_bf16(a[mi][1], b[ni][1], acc[mi][ni], 0, 0, 0);
            }
        __syncthreads();
    }
    #pragma unroll
    for (int mi = 0; mi < 4; ++mi)
        #pragma unroll
        for (int ni = 0; ni < 4; ++ni)
            #pragma unroll
            for (int r = 0; r < 4; ++r) {
                int row = m0 + wm*64 + mi*16 + (lane>>4)*4 + r;
                int col = n0 + wn*64 + ni*16 + (lane&15);
                float v = (acc[mi][ni][r] + bias[col]) * scale;
                int bb = row >> 11, l = row & (Lc-1);
                int hh = col >> 6,  hd = col & 63;
                dst[(((size_t)bb*Hc + hh)*Lc + l)*128 + half*64 + hd] = (__bf16)v;
            }
}

// ---------------------------------------------------------------------------
// vt: VT[bh][d 0..63][l 0..2047] = Kc[bh][l][d]
// ---------------------------------------------------------------------------
__global__ __launch_bounds__(256) void vt_kernel(
    const __bf16* __restrict__ Kc, __bf16* __restrict__ VT)
{
    const int l0 = blockIdx.x * 128, hb = blockIdx.y;
    const int t = threadIdx.x, w = t >> 6, lane = t & 63;
    __shared__ __bf16 T[128][72];
    const __bf16* src = Kc + ((size_t)hb*Lc + l0)*128;
    {
        const int lr = t >> 3, cc = t & 7;
        #pragma unroll
        for (int j = 0; j < 4; ++j)
            *(bf16x8*)&T[lr + j*32][cc*8] = *(const bf16x8*)(src + (size_t)(lr + j*32)*128 + cc*8);
    }
    __syncthreads();
    {
        const int d = lane;
        __bf16* dstp = VT + ((size_t)hb*64 + d)*Lc + l0 + w*32;
        #pragma unroll
        for (int j = 0; j < 4; ++j) {
            bf16x8 o;
            #pragma unroll
            for (int i = 0; i < 8; ++i) o[i] = T[w*32 + j*8 + i][d];
            *(bf16x8*)(dstp + j*8) = o;
        }
    }
}

// ---------------------------------------------------------------------------
// attn1: lsum pass. Fragment-major K chunks (conflict-free). Sync = r9.
// K chunk d = half*8 + ks: lane -> (kv half*32+(lane&31), k ks*16+(lane>>5)*8)
// ---------------------------------------------------------------------------
__global__ __launch_bounds__(256, 2) void attn1_kernel(
    const __bf16* __restrict__ Qc, const __bf16* __restrict__ Kc,
    const float* __restrict__ rel_bias, float* __restrict__ baddp)
{
    const int g = blockIdx.x;
    const int qt = g >> 5, hb = g & 31, h = hb & 15;
    const int q0 = qt * 128;
    const int t = threadIdx.x, lane = t & 63, w = t >> 6;
    const int ln31 = lane & 31, hi = lane >> 5;

    const __bf16* Qp = Qc + (size_t)hb * Lc * 128;
    const __bf16* Kp = Kc + (size_t)hb * Lc * 128;

    __shared__ __align__(16) char smem[49152];   // 3 x 16KB K buffers

    bf16x8 qa[8];
    {
        const __bf16* qrow = Qp + (size_t)(q0 + w*32 + ln31) * 128 + hi*8;
        #pragma unroll
        for (int ks = 0; ks < 8; ++ks) qa[ks] = *(const bf16x8*)(qrow + ks*16);
    }

    #define STAGE_K(B, KT) do { \
        const __bf16* kb_ = Kp + (size_t)(KT)*8192; \
        _Pragma("unroll") \
        for (int c = 0; c < 4; ++c) { \
            const int d = w*4 + c; \
            const int hf = d >> 3, ks = d & 7; \
            gl_lds16(kb_ + (size_t)(hf*32 + ln31)*128 + ks*16 + hi*8, \
                     smem + (B)*16384 + d*1024); \
        } \
    } while (0)
    #define KB0(B, KS) (*(const bf16x8*)(smem + (B)*16384 + (KS)*1024 + lane*16))
    #define KB1(B, KS) (*(const bf16x8*)(smem + (B)*16384 + (8+(KS))*1024 + lane*16))

    const float bc = rel_bias[h] * 0.18033688011112042f;
    float lp[4] = {0.f, 0.f, 0.f, 0.f};

    STAGE_K(0, 0); STAGE_K(1, 1);
    WAIT_VM4; BARRIER;
    for (int kt = 0; kt < NT; ++kt) {
        if (kt+2 < NT) STAGE_K((kt+2) % 3, kt+2);
        SBAR;
        const int buf = kt % 3;
        f32x16 s0, s1;
        #pragma unroll
        for (int r = 0; r < 16; ++r) { s0[r] = bc; s1[r] = bc; }
        __builtin_amdgcn_s_setprio(1);
        #pragma unroll
        for (int ks = 0; ks < 8; ++ks) {
            bf16x8 kb0 = KB0(buf, ks);
            bf16x8 kb1 = KB1(buf, ks);
            s0 = __builtin_amdgcn_mfma_f32_32x32x16_bf16(kb0, qa[ks], s0, 0, 0, 0);
            s1 = __builtin_amdgcn_mfma_f32_32x32x16_bf16(kb1, qa[ks], s1, 0, 0, 0);
        }
        __builtin_amdgcn_s_setprio(0);
        #pragma unroll
        for (int r = 0; r < 16; ++r) {
            lp[r & 3] += E2(s0[r]);
            lp[r & 3] += E2(s1[r]);
        }
        if (kt+2 < NT) { WAIT_VM4; } else { WAIT_VM0; }
        BARRIER;
    }
    float lsum = (lp[0] + lp[1]) + (lp[2] + lp[3]);
    lsum += __shfl_xor(lsum, 32);
    if (!hi) baddp[(size_t)hb*Lc + q0 + w*32 + ln31] = bc - log2f(lsum);
    #undef STAGE_K
    #undef KB0
    #undef KB1
}

// ---------------------------------------------------------------------------
// attn2: P out + PV. Fragment-major K/V chunks; Ps path + sync = r9 exactly.
// ---------------------------------------------------------------------------
__global__ __launch_bounds__(256, 2) void attn2_kernel(
    const __bf16* __restrict__ Qc, const __bf16* __restrict__ Kc,
    const __bf16* __restrict__ VT, const float* __restrict__ baddp,
    float* __restrict__ attn, __bf16* __restrict__ ctxh)
{
    const int g = blockIdx.x;
    const int qt = g >> 5, hb = g & 31, h = hb & 15, bb = hb >> 4;
    const int q0 = qt * 128;
    const int t = threadIdx.x, lane = t & 63, w = t >> 6;
    const int ln31 = lane & 31, hi = lane >> 5;

    const __bf16* Qp = Qc + (size_t)hb * Lc * 128;
    const __bf16* Kp = Kc + (size_t)hb * Lc * 128;
    const __bf16* Vp = VT + (size_t)hb * 64 * Lc;

    // LDS: K 3x16KB @0 | V 2x8KB @49152 | Ps 4x4KB @65536 = 80KB
    __shared__ __align__(16) char smem[81920];
    char* const VsB = smem + 49152;
    char* const PsW = smem + 65536 + w*4096;

    bf16x8 qa[8];
    {
        const __bf16* qrow = Qp + (size_t)(q0 + w*32 + ln31) * 128 + hi*8;
        #pragma unroll
        for (int ks = 0; ks < 8; ++ks) qa[ks] = *(const bf16x8*)(qrow + ks*16);
    }
    const float badd = baddp[(size_t)hb*Lc + q0 + w*32 + ln31];

    #define STAGE_K(B, KT) do { \
        const __bf16* kb_ = Kp + (size_t)(KT)*8192; \
        _Pragma("unroll") \
        for (int c = 0; c < 4; ++c) { \
            const int d = w*4 + c; \
            const int hf = d >> 3, ks = d & 7; \
            gl_lds16(kb_ + (size_t)(hf*32 + ln31)*128 + ks*16 + hi*8, \
                     smem + (B)*16384 + d*1024); \
        } \
    } while (0)
    #define STAGE_V(B, KT) do { \
        const __bf16* vb_ = Vp + (KT)*64; \
        _Pragma("unroll") \
        for (int c = 0; c < 2; ++c) { \
            const int d = w*2 + c; \
            const int hf = d >> 2, ks = d & 3; \
            gl_lds16(vb_ + (size_t)(hf*32 + ln31)*2048 + ks*16 + hi*8, \
                     VsB + (B)*8192 + d*1024); \
        } \
    } while (0)
    #define KB0(B, KS) (*(const bf16x8*)(smem + (B)*16384 + (KS)*1024 + lane*16))
    #define KB1(B, KS) (*(const bf16x8*)(smem + (B)*16384 + (8+(KS))*1024 + lane*16))
    #define VB0(B, KS) (*(const bf16x8*)(VsB + (B)*8192 + (KS)*1024 + lane*16))
    #define VB1(B, KS) (*(const bf16x8*)(VsB + (B)*8192 + (4+(KS))*1024 + lane*16))

    f32x16 ctx0 = {}, ctx1 = {};
    float* abase = attn + ((size_t)hb*Lc + q0 + w*32)*Lc;
    const int rr2 = lane >> 4;
    const int s8  = lane & 15;

    STAGE_K(0, 0); STAGE_V(0, 0); STAGE_K(1, 1);
    WAIT_VM4; BARRIER;

    for (int kt = 0; kt < NT; ++kt) {
        if (kt+1 < NT) STAGE_V((kt+1) & 1, kt+1);
        if (kt+2 < NT) STAGE_K((kt+2) % 3, kt+2);
        SBAR;
        const int buf = kt % 3;
        f32x16 s0, s1;
        #pragma unroll
        for (int r = 0; r < 16; ++r) { s0[r] = badd; s1[r] = badd; }
        __builtin_amdgcn_s_setprio(1);
        #pragma unroll
        for (int ks = 0; ks < 8; ++ks) {
            bf16x8 kb0 = KB0(buf, ks);
            bf16x8 kb1 = KB1(buf, ks);
            s0 = __builtin_amdgcn_mfma_f32_32x32x16_bf16(kb0, qa[ks], s0, 0, 0, 0);
            s1 = __builtin_amdgcn_mfma_f32_32x32x16_bf16(kb1, qa[ks], s1, 0, 0, 0);
        }
        __builtin_amdgcn_s_setprio(0);
        unsigned u0[8], u1[8], r0[8], r1[8];
        #pragma unroll
        for (int gq = 0; gq < 4; ++gq) {
            u0[gq]   = pkbf(E2(s0[4*gq+0]), E2(s0[4*gq+1]));
            u1[gq]   = pkbf(E2(s0[4*gq+2]), E2(s0[4*gq+3]));
            u0[4+gq] = pkbf(E2(s1[4*gq+0]), E2(s1[4*gq+1]));
            u1[4+gq] = pkbf(E2(s1[4*gq+2]), E2(s1[4*gq+3]));
        }
        #pragma unroll
        for (int gq = 0; gq < 8; ++gq) {
            r0[gq] = __shfl_xor(u0[gq], 32);
            r1[gq] = __shfl_xor(u1[gq], 32);
        }
        bf16x8 pb[4];
        #pragma unroll
        for (int ks = 0; ks < 4; ++ks) {
            const int gq = 2*ks + hi;
            U4 u;
            u.u[0] = hi ? r0[gq] : u0[gq];
            u.u[1] = hi ? r1[gq] : u1[gq];
            u.u[2] = hi ? u0[gq] : r0[gq];
            u.u[3] = hi ? u1[gq] : r1[gq];
            pb[ks] = u.v;
            *(bf16x8*)(PsW + ln31*128 + ((gq ^ (ln31 & 7))*16)) = u.v;
        }
        __builtin_amdgcn_s_setprio(1);
        #pragma unroll
        for (int ks = 0; ks < 4; ++ks) {
            bf16x8 v0 = VB0(kt & 1, ks);
            bf16x8 v1 = VB1(kt & 1, ks);
            ctx0 = __builtin_amdgcn_mfma_f32_32x32x16_bf16(pb[ks], v0, ctx0, 0, 0, 0);
            ctx1 = __builtin_amdgcn_mfma_f32_32x32x16_bf16(pb[ks], v1, ctx1, 0, 0, 0);
        }
        __builtin_amdgcn_s_setprio(0);
        WAIT_LG0; SBAR;
        #pragma unroll
        for (int j = 0; j < 8; ++j) {
            const int row = j*4 + rr2;
            u32x2 d = *(const u32x2*)(PsW + row*128 + (((s8>>1) ^ (row&7))*16) + (s8&1)*8);
            f32x4 o;
            o[0]=lo2f(d[0]); o[1]=hi2f(d[0]); o[2]=lo2f(d[1]); o[3]=hi2f(d[1]);
            __builtin_nontemporal_store(o, (f32x4*)(abase + (size_t)row*Lc + kt*64 + s8*4));
        }
        if (kt+1 < NT) {
            if (kt+2 < NT) { WAIT_VM12; } else { WAIT_VM8; }
            BARRIER;
        }
    }

    #pragma unroll
    for (int r = 0; r < 16; ++r) {
        const int R = (r&3) + 8*(r>>2) + 4*hi;
        const size_t row = (size_t)bb*Lc + q0 + w*32 + R;
        ctxh[row*Dc + h*64 + ln31]      = (__bf16)ctx0[r];
        ctxh[row*Dc + h*64 + 32 + ln31] = (__bf16)ctx1[r];
    }
    #undef STAGE_K
    #undef STAGE_V
    #undef KB0
    #undef KB1
    #undef VB0
    #undef VB1
}

// ---------------------------------------------------------------------------
// out: ctxh @ Wo + bo (B hi/lo). BK=64, fragment-major LDS, NT stores.
// ---------------------------------------------------------------------------
__global__ __launch_bounds__(256) void out_kernel(
    const __bf16* __restrict__ ctxh, const __bf16* __restrict__ Woh,
    const __bf16* __restrict__ Wol, const float* __restrict__ bo,
    float* __restrict__ out)
{
    const int m0 = blockIdx.y * 128, n0 = blockIdx.x * 128;
    const int t = threadIdx.x, lane = t & 63, w = t >> 6;
    const int wm = w >> 1, wn = w & 1;

    __shared__ __align__(16) char smem[49152];   // A @0 | Bh @16384 | Bl @32768

    f32x4 acc[4][4] = {};

    for (int k0 = 0; k0 < Dc; k0 += 64) {
        #pragma unroll
        for (int c = 0; c < 4; ++c) {
            const int d = w*4 + c;
            const int h = d >> 3, i = (d >> 1) & 3, kk = d & 1;
            const int rr = h*64 + i*16 + (lane & 15);
            const int kc = k0 + kk*32 + (lane >> 4)*8;
            gl_lds16(ctxh + (size_t)(m0 + rr)*Dc + kc, smem + d*1024);
            gl_lds16(Woh  + (size_t)(n0 + rr)*Dc + kc, smem + 16384 + d*1024);
            gl_lds16(Wol  + (size_t)(n0 + rr)*Dc + kc, smem + 32768 + d*1024);
        }
        WAIT_VM0; __syncthreads();
        bf16x8 a[4][2], bh[4][2], bl[4][2];
        #pragma unroll
        for (int i = 0; i < 4; ++i)
            #pragma unroll
            for (int kk = 0; kk < 2; ++kk) {
                a[i][kk]  = *(const bf16x8*)(smem + (wm*8 + i*2 + kk)*1024 + lane*16);
                bh[i][kk] = *(const bf16x8*)(smem + 16384 + (wn*8 + i*2 + kk)*1024 + lane*16);
                bl[i][kk] = *(const bf16x8*)(smem + 32768 + (wn*8 + i*2 + kk)*1024 + lane*16);
            }
        #pragma unroll
        for (int mi = 0; mi < 4; ++mi)
            #pragma unroll
            for (int ni = 0; ni < 4; ++ni) {
                acc[mi][ni] = __builtin_amdgcn_mfma_f32_16x16x32_bf16(a[mi][0], bh[ni][0], acc[mi][ni], 0, 0, 0);
                acc[mi][ni] = __builtin_amdgcn_mfma_f32_16x16x32_bf16(a[mi][0], bl[ni][0], acc[mi][ni], 0, 0, 0);
                acc[mi][ni] = __builtin_amdgcn_mfma_f32_16x16x32_bf16(a[mi][1], bh[ni][1], acc[mi][ni], 0, 0, 0);
                acc[mi][ni] = __builtin_amdgcn_mfma_f32_16x16x32_bf16(a[mi][1], bl[ni][1], acc[mi][ni], 0, 0, 0);
            }
        __syncthreads();
    }
    #pragma unroll
    for (int mi = 0; mi < 4; ++mi)
        #pragma unroll
        for (int ni = 0; ni < 4; ++ni)
            #pragma unroll
            for (int r = 0; r < 4; ++r) {
                int row = m0 + wm*64 + mi*16 + (lane>>4)*4 + r;
                int col = n0 + wn*64 + ni*16 + (lane&15);
                __builtin_nontemporal_store(acc[mi][ni][r] + bo[col],
                                            out + (size_t)row * Dc + col);
            }
}

// ---------------------------------------------------------------------------
extern "C" void kernel_launch(void* const* d_in, const int* in_sizes, int n_in,
                              void* d_out, int out_size, void* d_ws, size_t ws_size,
                              hipStream_t stream)
{
    const float* hidden = (const float*)d_in[0];
    const float* pos    = (const float*)d_in[1];
    const float* Wcq = (const float*)d_in[2];  const float* bcq = (const float*)d_in[3];
    const float* Wck = (const float*)d_in[4];  const float* bck = (const float*)d_in[5];
    const float* Wpq = (const float*)d_in[6];  const float* bpq = (const float*)d_in[7];
    const float* Wpk = (const float*)d_in[8];  const float* bpk = (const float*)d_in[9];
    const float* relb = (const float*)d_in[10];
    const float* Wo  = (const float*)d_in[11]; const float* bo  = (const float*)d_in[12];

    float* out  = (float*)d_out;
    float* attn = out + (size_t)Mc * Dc;

    // ws (bf16 elems): Woh[0,1M) Wol[1M,2M) Wt[2M,6M) (ctxh overlays Wt)
    // Qc[6M,14M) Kc[14M,22M) VT[22M,26M) badd f32 @26M
    __bf16* ws   = (__bf16*)d_ws;
    __bf16* Woh  = ws;
    __bf16* Wol  = ws + (1u<<20);
    __bf16* Wt   = ws + (2u<<20);
    __bf16* ctxh = Wt;
    __bf16* Qc   = ws + (6u<<20);
    __bf16* Kc   = ws + (14u<<20);
    __bf16* VTb  = ws + (22u<<20);
    float*  badd = (float*)(ws + (26u<<20));

    // bf16 casts of hidden/pos live in the attn output region (16 MB of 512 MB);
    // consumed by proj, overwritten later by attn2's P stores.
    __bf16* Xh = (__bf16*)attn;
    __bf16* Xp = Xh + (4u<<20);

    prep_kernel<<<dim3(16, 8, 7), 256, 0, stream>>>(
        hidden, pos, Wcq, Wck, Wpq, Wpk, Wo, Wt, Woh, Wol, Xh, Xp);
    proj_kernel<<<dim3(1024), 256, 0, stream>>>(Xh, Xp, Wt, bcq, bck, bpq, bpk, Qc, Kc);
    vt_kernel<<<dim3(Lc/128, 32), 256, 0, stream>>>(Kc, VTb);
    attn1_kernel<<<dim3(512), 256, 0, stream>>>(Qc, Kc, relb, badd);
    attn2_kernel<<<dim3(512), 256, 0, stream>>>(Qc, Kc, VTb, badd, attn, ctxh);
    out_kernel<<<dim3(8, 32), 256, 0, stream>>>(ctxh, Woh, Wol, bo, out);
}

// Round 11
// 330.330 us; speedup vs baseline: 1.0830x; 1.0830x over previous
//
#include <hip/hip_runtime.h>
#include <hip/hip_bf16.h>
#include <math.h>

// RaffelAttention round 11 = r9 (verified 326us) + two changes:
//  1. X pre-cast to bf16 in prep; proj stages A like B (halved bytes, no cvt).
//  2. attn1 launch_bounds(256,3) for 3 blocks/CU.
// attn1/attn2 sync + addressing otherwise byte-identical to r9.

#define Bc 2
#define Lc 2048
#define Dc 1024
#define Hc 16
#define Mc (Bc*Lc)
#define NT 32

typedef __attribute__((ext_vector_type(8))) __bf16 bf16x8;
typedef __attribute__((ext_vector_type(4))) float f32x4;
typedef __attribute__((ext_vector_type(16))) float f32x16;
typedef __attribute__((ext_vector_type(2))) unsigned u32x2;

union U4 { unsigned u[4]; bf16x8 v; };

__device__ __forceinline__ void gl_lds16(const void* g, void* l) {
    __builtin_amdgcn_global_load_lds(
        (const __attribute__((address_space(1))) void*)g,
        (__attribute__((address_space(3))) void*)l, 16, 0, 0);
}
__device__ __forceinline__ unsigned pkbf(float a, float b) {
    unsigned short ua = __builtin_bit_cast(unsigned short, (__bf16)a);
    unsigned short ub = __builtin_bit_cast(unsigned short, (__bf16)b);
    return (unsigned)ua | ((unsigned)ub << 16);
}
__device__ __forceinline__ float lo2f(unsigned u){ return __builtin_bit_cast(float, u << 16); }
__device__ __forceinline__ float hi2f(unsigned u){ return __builtin_bit_cast(float, u & 0xffff0000u); }
#define E2(x) __builtin_amdgcn_exp2f(x)

#define WAIT_VM0  asm volatile("s_waitcnt vmcnt(0)" ::: "memory")
#define WAIT_VM4  asm volatile("s_waitcnt vmcnt(4)" ::: "memory")
#define WAIT_VM8  asm volatile("s_waitcnt vmcnt(8)" ::: "memory")
#define WAIT_VM12 asm volatile("s_waitcnt vmcnt(12)" ::: "memory")
#define WAIT_LG0  asm volatile("s_waitcnt lgkmcnt(0)" ::: "memory")
#define SBAR __builtin_amdgcn_sched_barrier(0)
#define BARRIER do { __builtin_amdgcn_sched_barrier(0); __builtin_amdgcn_s_barrier(); __builtin_amdgcn_sched_barrier(0); } while (0)

// ---------------------------------------------------------------------------
// prep: z=0..3 Wt[z] bf16 [n][k]; z=4 Woh/Wol; z=5,6 cast hidden/pos to bf16.
// ---------------------------------------------------------------------------
__global__ __launch_bounds__(256) void prep_kernel(
    const float* __restrict__ hidden, const float* __restrict__ pos,
    const float* __restrict__ Wcq, const float* __restrict__ Wck,
    const float* __restrict__ Wpq, const float* __restrict__ Wpk,
    const float* __restrict__ Wo,
    __bf16* __restrict__ Wt, __bf16* __restrict__ Woh, __bf16* __restrict__ Wol,
    __bf16* __restrict__ Xh, __bf16* __restrict__ Xp)
{
    const int z = blockIdx.z;
    const int t = threadIdx.x;
    if (z >= 5) {   // straight cast
        const float* X = (z==5) ? hidden : pos;
        __bf16* dst    = (z==5) ? Xh : Xp;
        const size_t base = ((size_t)(blockIdx.y*16 + blockIdx.x)*256 + t) * 128;
        #pragma unroll
        for (int c = 0; c < 16; ++c) {
            const float* sp = X + base + c*8;
            float4 v0 = *(const float4*)sp;
            float4 v1 = *(const float4*)(sp + 4);
            bf16x8 o;
            o[0]=(__bf16)v0.x; o[1]=(__bf16)v0.y; o[2]=(__bf16)v0.z; o[3]=(__bf16)v0.w;
            o[4]=(__bf16)v1.x; o[5]=(__bf16)v1.y; o[6]=(__bf16)v1.z; o[7]=(__bf16)v1.w;
            *(bf16x8*)(dst + base + c*8) = o;
        }
        return;
    }
    const float* W = (z==0)?Wcq:(z==1)?Wck:(z==2)?Wpq:(z==3)?Wpk:Wo;
    const int n  = blockIdx.x*64 + (t & 63);
    const int k0 = blockIdx.y*128 + (t >> 6)*32;
    float v[32];
    #pragma unroll
    for (int j = 0; j < 32; ++j) v[j] = W[(size_t)(k0+j)*Dc + n];
    if (z < 4) {
        __bf16* dst = Wt + (size_t)z*Dc*Dc + (size_t)n*Dc + k0;
        #pragma unroll
        for (int c = 0; c < 4; ++c) {
            bf16x8 o;
            #pragma unroll
            for (int j = 0; j < 8; ++j) o[j] = (__bf16)v[c*8+j];
            *(bf16x8*)(dst + c*8) = o;
        }
    } else {
        __bf16* dh = Woh + (size_t)n*Dc + k0;
        __bf16* dl = Wol + (size_t)n*Dc + k0;
        #pragma unroll
        for (int c = 0; c < 4; ++c) {
            bf16x8 oh, ol;
            #pragma unroll
            for (int j = 0; j < 8; ++j) {
                float x = v[c*8+j];
                __bf16 hi = (__bf16)x;
                oh[j] = hi; ol[j] = (__bf16)(x - (float)hi);
            }
            *(bf16x8*)(dh + c*8) = oh;
            *(bf16x8*)(dl + c*8) = ol;
        }
    }
}

// ---------------------------------------------------------------------------
// proj: X(bf16) @ Wt[z](bf16,[n][k]) -> Q'/K'. BK=32; A and B staged
// identically (16 rows x 64B per gl_lds, XOR-swizzled 16B slots).
// ---------------------------------------------------------------------------
__global__ __launch_bounds__(256) void proj_kernel(
    const __bf16* __restrict__ Xh, const __bf16* __restrict__ Xp,
    const __bf16* __restrict__ Wt,
    const float* __restrict__ bcq, const float* __restrict__ bck,
    const float* __restrict__ bpq, const float* __restrict__ bpk,
    __bf16* __restrict__ Qc, __bf16* __restrict__ Kc)
{
    const int g = blockIdx.x;
    const int nblk = g >> 7, sg = g & 127, mblk = sg & 31, z = sg >> 5;
    const int m0 = mblk*128, n0 = nblk*128;
    const __bf16* X = (z < 2) ? Xh : Xp;
    const __bf16* Wz = Wt + (size_t)z*Dc*Dc;
    const float* bias = (z==0)?bcq:(z==1)?bck:(z==2)?bpq:bpk;
    __bf16* dst = (z & 1) ? Kc : Qc;
    const int half = z >> 1;
    const float scale = (z & 1) ? 1.0f : 0.18033688011112042f; // 0.125*log2e on Q

    const int t = threadIdx.x, lane = t & 63, w = t >> 6;
    const int wm = w >> 1, wn = w & 1;

    __shared__ __align__(16) __bf16 As[128][32];
    __shared__ __align__(16) __bf16 Bs[128][32];

    const int brow4 = lane >> 2;                       // 0..15
    const int bcol  = ((lane & 3) ^ (brow4 & 3)) * 8;  // bf16 col, swizzled

    f32x4 acc[4][4] = {};

    for (int k0 = 0; k0 < Dc; k0 += 32) {
        #pragma unroll
        for (int i = 0; i < 2; ++i) {
            int row = 16*(2*w+i) + brow4;
            gl_lds16(X  + (size_t)(m0+row)*Dc + k0 + bcol, (char*)As + (2*w+i)*1024);
            gl_lds16(Wz + (size_t)(n0+row)*Dc + k0 + bcol, (char*)Bs + (2*w+i)*1024);
        }
        WAIT_VM0; __syncthreads();
        bf16x8 a[4], b[4];
        const int s2 = lane >> 4;
        #pragma unroll
        for (int i = 0; i < 4; ++i) {
            int Ra = wm*64 + i*16 + (lane&15);
            int Rb = wn*64 + i*16 + (lane&15);
            a[i] = *(const bf16x8*)((const char*)&As[Ra][0] + ((s2 ^ (Ra&3))*16));
            b[i] = *(const bf16x8*)((const char*)&Bs[Rb][0] + ((s2 ^ (Rb&3))*16));
        }
        #pragma unroll
        for (int mi = 0; mi < 4; ++mi)
            #pragma unroll
            for (int ni = 0; ni < 4; ++ni)
                acc[mi][ni] = __builtin_amdgcn_mfma_f32_16x16x32_bf16(a[mi], b[ni], acc[mi][ni], 0, 0, 0);
        __syncthreads();
    }
    #pragma unroll
    for (int mi = 0; mi < 4; ++mi)
        #pragma unroll
        for (int ni = 0; ni < 4; ++ni)
            #pragma unroll
            for (int r = 0; r < 4; ++r) {
                int row = m0 + wm*64 + mi*16 + (lane>>4)*4 + r;
                int col = n0 + wn*64 + ni*16 + (lane&15);
                float v = (acc[mi][ni][r] + bias[col]) * scale;
                int bb = row >> 11, l = row & (Lc-1);
                int hh = col >> 6,  hd = col & 63;
                dst[(((size_t)bb*Hc + hh)*Lc + l)*128 + half*64 + hd] = (__bf16)v;
            }
}

// ---------------------------------------------------------------------------
// vt: VT[bh][d 0..63][l 0..2047] = Kc[bh][l][d]
// ---------------------------------------------------------------------------
__global__ __launch_bounds__(256) void vt_kernel(
    const __bf16* __restrict__ Kc, __bf16* __restrict__ VT)
{
    const int l0 = blockIdx.x * 128, hb = blockIdx.y;
    const int t = threadIdx.x, w = t >> 6, lane = t & 63;
    __shared__ __bf16 T[128][72];
    const __bf16* src = Kc + ((size_t)hb*Lc + l0)*128;
    {
        const int lr = t >> 3, cc = t & 7;
        #pragma unroll
        for (int j = 0; j < 4; ++j)
            *(bf16x8*)&T[lr + j*32][cc*8] = *(const bf16x8*)(src + (size_t)(lr + j*32)*128 + cc*8);
    }
    __syncthreads();
    {
        const int d = lane;
        __bf16* dstp = VT + ((size_t)hb*64 + d)*Lc + l0 + w*32;
        #pragma unroll
        for (int j = 0; j < 4; ++j) {
            bf16x8 o;
            #pragma unroll
            for (int i = 0; i < 8; ++i) o[i] = T[w*32 + j*8 + i][d];
            *(bf16x8*)(dstp + j*8) = o;
        }
    }
}

// ---------------------------------------------------------------------------
// attn1: lsum pass (r9 body, launch_bounds(256,3) for 3 blocks/CU).
// ---------------------------------------------------------------------------
__global__ __launch_bounds__(256, 3) void attn1_kernel(
    const __bf16* __restrict__ Qc, const __bf16* __restrict__ Kc,
    const float* __restrict__ rel_bias, float* __restrict__ baddp)
{
    const int g = blockIdx.x;
    const int qt = g >> 5, hb = g & 31, h = hb & 15;
    const int q0 = qt * 128;
    const int t = threadIdx.x, lane = t & 63, w = t >> 6;
    const int ln31 = lane & 31, hi = lane >> 5;

    const __bf16* Qp = Qc + (size_t)hb * Lc * 128;
    const __bf16* Kp = Kc + (size_t)hb * Lc * 128;

    __shared__ __align__(16) char smem[49152];   // 3 x 16KB K buffers

    bf16x8 qa[8];
    {
        const __bf16* qrow = Qp + (size_t)(q0 + w*32 + ln31) * 128 + hi*8;
        #pragma unroll
        for (int ks = 0; ks < 8; ++ks) qa[ks] = *(const bf16x8*)(qrow + ks*16);
    }

    int kof[4];
    #pragma unroll
    for (int c = 0; c < 4; ++c) {
        int rl = c*4 + (lane >> 4);
        int rr = w*16 + rl;
        kof[c] = rr*128 + (((lane & 15) ^ rl) * 8);
    }
    int kR[8];
    #pragma unroll
    for (int ks = 0; ks < 8; ++ks) kR[ks] = ((ks*2 + hi) ^ (lane & 15)) * 8;

    #define STAGE_K(B, KT) do { \
        const __bf16* kb_ = Kp + (size_t)(KT)*8192; \
        gl_lds16(kb_ + kof[0], smem + ((B)*64 + w*16 +  0)*256); \
        gl_lds16(kb_ + kof[1], smem + ((B)*64 + w*16 +  4)*256); \
        gl_lds16(kb_ + kof[2], smem + ((B)*64 + w*16 +  8)*256); \
        gl_lds16(kb_ + kof[3], smem + ((B)*64 + w*16 + 12)*256); \
    } while (0)
    #define KB(B, ROW, KS) (*(const bf16x8*)(smem + ((B)*64 + (ROW))*256 + kR[KS]*2))

    const float bc = rel_bias[h] * 0.18033688011112042f;
    float lp[4] = {0.f, 0.f, 0.f, 0.f};

    STAGE_K(0, 0); STAGE_K(1, 1);
    WAIT_VM4; BARRIER;
    for (int kt = 0; kt < NT; ++kt) {
        if (kt+2 < NT) STAGE_K((kt+2) % 3, kt+2);
        SBAR;
        const int buf = kt % 3;
        f32x16 s0, s1;
        #pragma unroll
        for (int r = 0; r < 16; ++r) { s0[r] = bc; s1[r] = bc; }
        __builtin_amdgcn_s_setprio(1);
        #pragma unroll
        for (int ks = 0; ks < 8; ++ks) {
            bf16x8 kb0 = KB(buf, ln31, ks);
            bf16x8 kb1 = KB(buf, 32 + ln31, ks);
            s0 = __builtin_amdgcn_mfma_f32_32x32x16_bf16(kb0, qa[ks], s0, 0, 0, 0);
            s1 = __builtin_amdgcn_mfma_f32_32x32x16_bf16(kb1, qa[ks], s1, 0, 0, 0);
        }
        __builtin_amdgcn_s_setprio(0);
        #pragma unroll
        for (int r = 0; r < 16; ++r) {
            lp[r & 3] += E2(s0[r]);
            lp[r & 3] += E2(s1[r]);
        }
        if (kt+2 < NT) { WAIT_VM4; } else { WAIT_VM0; }
        BARRIER;
    }
    float lsum = (lp[0] + lp[1]) + (lp[2] + lp[3]);
    lsum += __shfl_xor(lsum, 32);
    if (!hi) baddp[(size_t)hb*Lc + q0 + w*32 + ln31] = bc - log2f(lsum);
    #undef STAGE_K
    #undef KB
}

// ---------------------------------------------------------------------------
// attn2: P out + PV (r9 body, unchanged).
// ---------------------------------------------------------------------------
__global__ __launch_bounds__(256, 2) void attn2_kernel(
    const __bf16* __restrict__ Qc, const __bf16* __restrict__ Kc,
    const __bf16* __restrict__ VT, const float* __restrict__ baddp,
    float* __restrict__ attn, __bf16* __restrict__ ctxh)
{
    const int g = blockIdx.x;
    const int qt = g >> 5, hb = g & 31, h = hb & 15, bb = hb >> 4;
    const int q0 = qt * 128;
    const int t = threadIdx.x, lane = t & 63, w = t >> 6;
    const int ln31 = lane & 31, hi = lane >> 5;

    const __bf16* Qp = Qc + (size_t)hb * Lc * 128;
    const __bf16* Kp = Kc + (size_t)hb * Lc * 128;
    const __bf16* Vp = VT + (size_t)hb * 64 * Lc;

    // LDS: K 3x16KB @0 | V 2x8KB @49152 | Ps 4x4KB @65536 = 80KB
    __shared__ __align__(16) char smem[81920];
    char* const VsB = smem + 49152;
    char* const PsW = smem + 65536 + w*4096;

    bf16x8 qa[8];
    {
        const __bf16* qrow = Qp + (size_t)(q0 + w*32 + ln31) * 128 + hi*8;
        #pragma unroll
        for (int ks = 0; ks < 8; ++ks) qa[ks] = *(const bf16x8*)(qrow + ks*16);
    }
    const float badd = baddp[(size_t)hb*Lc + q0 + w*32 + ln31];

    int kof[4];
    #pragma unroll
    for (int c = 0; c < 4; ++c) {
        int rl = c*4 + (lane >> 4);
        int rr = w*16 + rl;
        kof[c] = rr*128 + (((lane & 15) ^ rl) * 8);
    }
    int vof[2];
    #pragma unroll
    for (int c = 0; c < 2; ++c) {
        int dl = lane >> 3;
        int dd = w*16 + c*8 + dl;
        vof[c] = dd*2048 + (((lane & 7) ^ dl) * 8);
    }
    int kR[8];
    #pragma unroll
    for (int ks = 0; ks < 8; ++ks) kR[ks] = ((ks*2 + hi) ^ (lane & 15)) * 8;
    int vR[4];
    #pragma unroll
    for (int ks = 0; ks < 4; ++ks) vR[ks] = ((ks*2 + hi) ^ (lane & 7)) * 8;

    #define STAGE_K(B, KT) do { \
        const __bf16* kb_ = Kp + (size_t)(KT)*8192; \
        gl_lds16(kb_ + kof[0], smem + ((B)*64 + w*16 +  0)*256); \
        gl_lds16(kb_ + kof[1], smem + ((B)*64 + w*16 +  4)*256); \
        gl_lds16(kb_ + kof[2], smem + ((B)*64 + w*16 +  8)*256); \
        gl_lds16(kb_ + kof[3], smem + ((B)*64 + w*16 + 12)*256); \
    } while (0)
    #define STAGE_V(B, KT) do { \
        const __bf16* vb_ = Vp + (KT)*64; \
        gl_lds16(vb_ + vof[0], VsB + ((B)*64 + w*16 + 0)*128); \
        gl_lds16(vb_ + vof[1], VsB + ((B)*64 + w*16 + 8)*128); \
    } while (0)
    #define KB(B, ROW, KS) (*(const bf16x8*)(smem + ((B)*64 + (ROW))*256 + kR[KS]*2))
    #define VB(B, ROW, KS) (*(const bf16x8*)(VsB  + ((B)*64 + (ROW))*128 + vR[KS]*2))

    f32x16 ctx0 = {}, ctx1 = {};
    float* abase = attn + ((size_t)hb*Lc + q0 + w*32)*Lc;
    const int rr2 = lane >> 4;
    const int s8  = lane & 15;

    STAGE_K(0, 0); STAGE_V(0, 0); STAGE_K(1, 1);
    WAIT_VM4; BARRIER;

    for (int kt = 0; kt < NT; ++kt) {
        if (kt+1 < NT) STAGE_V((kt+1) & 1, kt+1);
        if (kt+2 < NT) STAGE_K((kt+2) % 3, kt+2);
        SBAR;
        const int buf = kt % 3;
        f32x16 s0, s1;
        #pragma unroll
        for (int r = 0; r < 16; ++r) { s0[r] = badd; s1[r] = badd; }
        __builtin_amdgcn_s_setprio(1);
        #pragma unroll
        for (int ks = 0; ks < 8; ++ks) {
            bf16x8 kb0 = KB(buf, ln31, ks);
            bf16x8 kb1 = KB(buf, 32 + ln31, ks);
            s0 = __builtin_amdgcn_mfma_f32_32x32x16_bf16(kb0, qa[ks], s0, 0, 0, 0);
            s1 = __builtin_amdgcn_mfma_f32_32x32x16_bf16(kb1, qa[ks], s1, 0, 0, 0);
        }
        __builtin_amdgcn_s_setprio(0);
        unsigned u0[8], u1[8], r0[8], r1[8];
        #pragma unroll
        for (int gq = 0; gq < 4; ++gq) {
            u0[gq]   = pkbf(E2(s0[4*gq+0]), E2(s0[4*gq+1]));
            u1[gq]   = pkbf(E2(s0[4*gq+2]), E2(s0[4*gq+3]));
            u0[4+gq] = pkbf(E2(s1[4*gq+0]), E2(s1[4*gq+1]));
            u1[4+gq] = pkbf(E2(s1[4*gq+2]), E2(s1[4*gq+3]));
        }
        #pragma unroll
        for (int gq = 0; gq < 8; ++gq) {
            r0[gq] = __shfl_xor(u0[gq], 32);
            r1[gq] = __shfl_xor(u1[gq], 32);
        }
        bf16x8 pb[4];
        #pragma unroll
        for (int ks = 0; ks < 4; ++ks) {
            const int gq = 2*ks + hi;
            U4 u;
            u.u[0] = hi ? r0[gq] : u0[gq];
            u.u[1] = hi ? r1[gq] : u1[gq];
            u.u[2] = hi ? u0[gq] : r0[gq];
            u.u[3] = hi ? u1[gq] : r1[gq];
            pb[ks] = u.v;
            *(bf16x8*)(PsW + ln31*128 + ((gq ^ (ln31 & 7))*16)) = u.v;
        }
        __builtin_amdgcn_s_setprio(1);
        #pragma unroll
        for (int ks = 0; ks < 4; ++ks) {
            bf16x8 v0 = VB(kt & 1, ln31, ks);
            bf16x8 v1 = VB(kt & 1, 32 + ln31, ks);
            ctx0 = __builtin_amdgcn_mfma_f32_32x32x16_bf16(pb[ks], v0, ctx0, 0, 0, 0);
            ctx1 = __builtin_amdgcn_mfma_f32_32x32x16_bf16(pb[ks], v1, ctx1, 0, 0, 0);
        }
        __builtin_amdgcn_s_setprio(0);
        WAIT_LG0; SBAR;
        #pragma unroll
        for (int j = 0; j < 8; ++j) {
            const int row = j*4 + rr2;
            u32x2 d = *(const u32x2*)(PsW + row*128 + (((s8>>1) ^ (row&7))*16) + (s8&1)*8);
            f32x4 o;
            o[0]=lo2f(d[0]); o[1]=hi2f(d[0]); o[2]=lo2f(d[1]); o[3]=hi2f(d[1]);
            __builtin_nontemporal_store(o, (f32x4*)(abase + (size_t)row*Lc + kt*64 + s8*4));
        }
        if (kt+1 < NT) {
            if (kt+2 < NT) { WAIT_VM12; } else { WAIT_VM8; }
            BARRIER;
        }
    }

    #pragma unroll
    for (int r = 0; r < 16; ++r) {
        const int R = (r&3) + 8*(r>>2) + 4*hi;
        const size_t row = (size_t)bb*Lc + q0 + w*32 + R;
        ctxh[row*Dc + h*64 + ln31]      = (__bf16)ctx0[r];
        ctxh[row*Dc + h*64 + 32 + ln31] = (__bf16)ctx1[r];
    }
    #undef STAGE_K
    #undef STAGE_V
    #undef KB
    #undef VB
}

// ---------------------------------------------------------------------------
// out: ctxh(bf16) @ Wo + bo, B split hi/lo (r9 body, unchanged).
// ---------------------------------------------------------------------------
__global__ __launch_bounds__(256) void out_kernel(
    const __bf16* __restrict__ ctxh, const __bf16* __restrict__ Woh,
    const __bf16* __restrict__ Wol, const float* __restrict__ bo,
    float* __restrict__ out)
{
    const int m0 = blockIdx.y * 128, n0 = blockIdx.x * 128;
    const int t = threadIdx.x, lane = t & 63, w = t >> 6;
    const int wm = w >> 1, wn = w & 1;

    __shared__ __align__(16) __bf16 As[128][32];
    __shared__ __align__(16) __bf16 Bh[128][32];
    __shared__ __align__(16) __bf16 Bl[128][32];

    const int row4 = lane >> 2;
    const int scol = ((lane & 3) ^ (row4 & 3)) * 8;

    f32x4 acc[4][4] = {};

    for (int k0 = 0; k0 < Dc; k0 += 32) {
        #pragma unroll
        for (int i = 0; i < 2; ++i) {
            int row = 16*(2*w+i) + row4;
            gl_lds16(ctxh + (size_t)(m0+row)*Dc + k0 + scol, (char*)As + (2*w+i)*1024);
            gl_lds16(Woh  + (size_t)(n0+row)*Dc + k0 + scol, (char*)Bh + (2*w+i)*1024);
            gl_lds16(Wol  + (size_t)(n0+row)*Dc + k0 + scol, (char*)Bl + (2*w+i)*1024);
        }
        WAIT_VM0; __syncthreads();
        bf16x8 a[4], bh[4], bl[4];
        const int s2 = lane >> 4;
        #pragma unroll
        for (int i = 0; i < 4; ++i) {
            int Ra = wm*64 + i*16 + (lane&15);
            int Rb = wn*64 + i*16 + (lane&15);
            a[i]  = *(const bf16x8*)((const char*)&As[Ra][0] + ((s2 ^ (Ra&3))*16));
            bh[i] = *(const bf16x8*)((const char*)&Bh[Rb][0] + ((s2 ^ (Rb&3))*16));
            bl[i] = *(const bf16x8*)((const char*)&Bl[Rb][0] + ((s2 ^ (Rb&3))*16));
        }
        #pragma unroll
        for (int mi = 0; mi < 4; ++mi)
            #pragma unroll
            for (int ni = 0; ni < 4; ++ni) {
                acc[mi][ni] = __builtin_amdgcn_mfma_f32_16x16x32_bf16(a[mi], bh[ni], acc[mi][ni], 0, 0, 0);
                acc[mi][ni] = __builtin_amdgcn_mfma_f32_16x16x32_bf16(a[mi], bl[ni], acc[mi][ni], 0, 0, 0);
            }
        __syncthreads();
    }
    #pragma unroll
    for (int mi = 0; mi < 4; ++mi)
        #pragma unroll
        for (int ni = 0; ni < 4; ++ni)
            #pragma unroll
            for (int r = 0; r < 4; ++r) {
                int row = m0 + wm*64 + mi*16 + (lane>>4)*4 + r;
                int col = n0 + wn*64 + ni*16 + (lane&15);
                __builtin_nontemporal_store(acc[mi][ni][r] + bo[col],
                                            out + (size_t)row * Dc + col);
            }
}

// ---------------------------------------------------------------------------
extern "C" void kernel_launch(void* const* d_in, const int* in_sizes, int n_in,
                              void* d_out, int out_size, void* d_ws, size_t ws_size,
                              hipStream_t stream)
{
    const float* hidden = (const float*)d_in[0];
    const float* pos    = (const float*)d_in[1];
    const float* Wcq = (const float*)d_in[2];  const float* bcq = (const float*)d_in[3];
    const float* Wck = (const float*)d_in[4];  const float* bck = (const float*)d_in[5];
    const float* Wpq = (const float*)d_in[6];  const float* bpq = (const float*)d_in[7];
    const float* Wpk = (const float*)d_in[8];  const float* bpk = (const float*)d_in[9];
    const float* relb = (const float*)d_in[10];
    const float* Wo  = (const float*)d_in[11]; const float* bo  = (const float*)d_in[12];

    float* out  = (float*)d_out;
    float* attn = out + (size_t)Mc * Dc;

    // ws (bf16 elems): Woh[0,1M) Wol[1M,2M) Wt[2M,6M) (ctxh overlays Wt)
    // Qc[6M,14M) Kc[14M,22M) VT[22M,26M) badd f32 @26M
    __bf16* ws   = (__bf16*)d_ws;
    __bf16* Woh  = ws;
    __bf16* Wol  = ws + (1u<<20);
    __bf16* Wt   = ws + (2u<<20);
    __bf16* ctxh = Wt;
    __bf16* Qc   = ws + (6u<<20);
    __bf16* Kc   = ws + (14u<<20);
    __bf16* VTb  = ws + (22u<<20);
    float*  badd = (float*)(ws + (26u<<20));

    // bf16 casts of hidden/pos live in the attn output region (16 MB of 512 MB);
    // consumed by proj, overwritten later by attn2's P stores.
    __bf16* Xh = (__bf16*)attn;
    __bf16* Xp = Xh + (4u<<20);

    prep_kernel<<<dim3(16, 8, 7), 256, 0, stream>>>(
        hidden, pos, Wcq, Wck, Wpq, Wpk, Wo, Wt, Woh, Wol, Xh, Xp);
    proj_kernel<<<dim3(1024), 256, 0, stream>>>(Xh, Xp, Wt, bcq, bck, bpq, bpk, Qc, Kc);
    vt_kernel<<<dim3(Lc/128, 32), 256, 0, stream>>>(Kc, VTb);
    attn1_kernel<<<dim3(512), 256, 0, stream>>>(Qc, Kc, relb, badd);
    attn2_kernel<<<dim3(512), 256, 0, stream>>>(Qc, Kc, VTb, badd, attn, ctxh);
    out_kernel<<<dim3(8, 32), 256, 0, stream>>>(ctxh, Woh, Wol, bo, out);
}

// Round 12
// 310.129 us; speedup vs baseline: 1.1536x; 1.0651x over previous
//
#include <hip/hip_runtime.h>
#include <hip/hip_bf16.h>
#include <math.h>

// RaffelAttention round 12 = r11 with proj/out converted to the attn1-verified
// 3-buffer counted-vmcnt pipeline (prefetch 2 ahead, one barrier/iter).
// attn1/attn2/prep/vt byte-identical to r11.

#define Bc 2
#define Lc 2048
#define Dc 1024
#define Hc 16
#define Mc (Bc*Lc)
#define NT 32

typedef __attribute__((ext_vector_type(8))) __bf16 bf16x8;
typedef __attribute__((ext_vector_type(4))) float f32x4;
typedef __attribute__((ext_vector_type(16))) float f32x16;
typedef __attribute__((ext_vector_type(2))) unsigned u32x2;

union U4 { unsigned u[4]; bf16x8 v; };

__device__ __forceinline__ void gl_lds16(const void* g, void* l) {
    __builtin_amdgcn_global_load_lds(
        (const __attribute__((address_space(1))) void*)g,
        (__attribute__((address_space(3))) void*)l, 16, 0, 0);
}
__device__ __forceinline__ unsigned pkbf(float a, float b) {
    unsigned short ua = __builtin_bit_cast(unsigned short, (__bf16)a);
    unsigned short ub = __builtin_bit_cast(unsigned short, (__bf16)b);
    return (unsigned)ua | ((unsigned)ub << 16);
}
__device__ __forceinline__ float lo2f(unsigned u){ return __builtin_bit_cast(float, u << 16); }
__device__ __forceinline__ float hi2f(unsigned u){ return __builtin_bit_cast(float, u & 0xffff0000u); }
#define E2(x) __builtin_amdgcn_exp2f(x)

#define WAIT_VM0  asm volatile("s_waitcnt vmcnt(0)" ::: "memory")
#define WAIT_VM4  asm volatile("s_waitcnt vmcnt(4)" ::: "memory")
#define WAIT_VM6  asm volatile("s_waitcnt vmcnt(6)" ::: "memory")
#define WAIT_VM8  asm volatile("s_waitcnt vmcnt(8)" ::: "memory")
#define WAIT_VM12 asm volatile("s_waitcnt vmcnt(12)" ::: "memory")
#define WAIT_LG0  asm volatile("s_waitcnt lgkmcnt(0)" ::: "memory")
#define SBAR __builtin_amdgcn_sched_barrier(0)
#define BARRIER do { __builtin_amdgcn_sched_barrier(0); __builtin_amdgcn_s_barrier(); __builtin_amdgcn_sched_barrier(0); } while (0)

// ---------------------------------------------------------------------------
// prep: z=0..3 Wt[z] bf16 [n][k]; z=4 Woh/Wol; z=5,6 cast hidden/pos to bf16.
// ---------------------------------------------------------------------------
__global__ __launch_bounds__(256) void prep_kernel(
    const float* __restrict__ hidden, const float* __restrict__ pos,
    const float* __restrict__ Wcq, const float* __restrict__ Wck,
    const float* __restrict__ Wpq, const float* __restrict__ Wpk,
    const float* __restrict__ Wo,
    __bf16* __restrict__ Wt, __bf16* __restrict__ Woh, __bf16* __restrict__ Wol,
    __bf16* __restrict__ Xh, __bf16* __restrict__ Xp)
{
    const int z = blockIdx.z;
    const int t = threadIdx.x;
    if (z >= 5) {   // straight cast
        const float* X = (z==5) ? hidden : pos;
        __bf16* dst    = (z==5) ? Xh : Xp;
        const size_t base = ((size_t)(blockIdx.y*16 + blockIdx.x)*256 + t) * 128;
        #pragma unroll
        for (int c = 0; c < 16; ++c) {
            const float* sp = X + base + c*8;
            float4 v0 = *(const float4*)sp;
            float4 v1 = *(const float4*)(sp + 4);
            bf16x8 o;
            o[0]=(__bf16)v0.x; o[1]=(__bf16)v0.y; o[2]=(__bf16)v0.z; o[3]=(__bf16)v0.w;
            o[4]=(__bf16)v1.x; o[5]=(__bf16)v1.y; o[6]=(__bf16)v1.z; o[7]=(__bf16)v1.w;
            *(bf16x8*)(dst + base + c*8) = o;
        }
        return;
    }
    const float* W = (z==0)?Wcq:(z==1)?Wck:(z==2)?Wpq:(z==3)?Wpk:Wo;
    const int n  = blockIdx.x*64 + (t & 63);
    const int k0 = blockIdx.y*128 + (t >> 6)*32;
    float v[32];
    #pragma unroll
    for (int j = 0; j < 32; ++j) v[j] = W[(size_t)(k0+j)*Dc + n];
    if (z < 4) {
        __bf16* dst = Wt + (size_t)z*Dc*Dc + (size_t)n*Dc + k0;
        #pragma unroll
        for (int c = 0; c < 4; ++c) {
            bf16x8 o;
            #pragma unroll
            for (int j = 0; j < 8; ++j) o[j] = (__bf16)v[c*8+j];
            *(bf16x8*)(dst + c*8) = o;
        }
    } else {
        __bf16* dh = Woh + (size_t)n*Dc + k0;
        __bf16* dl = Wol + (size_t)n*Dc + k0;
        #pragma unroll
        for (int c = 0; c < 4; ++c) {
            bf16x8 oh, ol;
            #pragma unroll
            for (int j = 0; j < 8; ++j) {
                float x = v[c*8+j];
                __bf16 hi = (__bf16)x;
                oh[j] = hi; ol[j] = (__bf16)(x - (float)hi);
            }
            *(bf16x8*)(dh + c*8) = oh;
            *(bf16x8*)(dl + c*8) = ol;
        }
    }
}

// ---------------------------------------------------------------------------
// proj: X(bf16) @ Wt[z](bf16,[n][k]) -> Q'/K'. BK=32, 3-buffer counted-vmcnt
// pipeline (attn1 schedule). Addressing identical to r11.
// ---------------------------------------------------------------------------
__global__ __launch_bounds__(256) void proj_kernel(
    const __bf16* __restrict__ Xh, const __bf16* __restrict__ Xp,
    const __bf16* __restrict__ Wt,
    const float* __restrict__ bcq, const float* __restrict__ bck,
    const float* __restrict__ bpq, const float* __restrict__ bpk,
    __bf16* __restrict__ Qc, __bf16* __restrict__ Kc)
{
    const int g = blockIdx.x;
    const int nblk = g >> 7, sg = g & 127, mblk = sg & 31, z = sg >> 5;
    const int m0 = mblk*128, n0 = nblk*128;
    const __bf16* X = (z < 2) ? Xh : Xp;
    const __bf16* Wz = Wt + (size_t)z*Dc*Dc;
    const float* bias = (z==0)?bcq:(z==1)?bck:(z==2)?bpq:bpk;
    __bf16* dst = (z & 1) ? Kc : Qc;
    const int half = z >> 1;
    const float scale = (z & 1) ? 1.0f : 0.18033688011112042f; // 0.125*log2e on Q

    const int t = threadIdx.x, lane = t & 63, w = t >> 6;
    const int wm = w >> 1, wn = w & 1;

    __shared__ __align__(16) char smem[49152];   // 3 x (A 8KB | B 8KB)

    const int brow4 = lane >> 2;                       // 0..15
    const int bcol  = ((lane & 3) ^ (brow4 & 3)) * 8;  // bf16 col, swizzled

    f32x4 acc[4][4] = {};

    #define STAGE_P(B, KT) do { \
        const int k0_ = (KT)*32; \
        _Pragma("unroll") \
        for (int i = 0; i < 2; ++i) { \
            int row = 16*(2*w+i) + brow4; \
            gl_lds16(X  + (size_t)(m0+row)*Dc + k0_ + bcol, smem + (B)*16384 + (2*w+i)*1024); \
            gl_lds16(Wz + (size_t)(n0+row)*Dc + k0_ + bcol, smem + (B)*16384 + 8192 + (2*w+i)*1024); \
        } \
    } while (0)

    STAGE_P(0, 0); STAGE_P(1, 1);
    WAIT_VM4; BARRIER;
    for (int kt = 0; kt < 32; ++kt) {
        if (kt+2 < 32) STAGE_P((kt+2) % 3, kt+2);
        SBAR;
        const int buf = kt % 3;
        bf16x8 a[4], b[4];
        const int s2 = lane >> 4;
        #pragma unroll
        for (int i = 0; i < 4; ++i) {
            int Ra = wm*64 + i*16 + (lane&15);
            int Rb = wn*64 + i*16 + (lane&15);
            a[i] = *(const bf16x8*)(smem + buf*16384 + Ra*64 + ((s2 ^ (Ra&3))*16));
            b[i] = *(const bf16x8*)(smem + buf*16384 + 8192 + Rb*64 + ((s2 ^ (Rb&3))*16));
        }
        __builtin_amdgcn_s_setprio(1);
        #pragma unroll
        for (int mi = 0; mi < 4; ++mi)
            #pragma unroll
            for (int ni = 0; ni < 4; ++ni)
                acc[mi][ni] = __builtin_amdgcn_mfma_f32_16x16x32_bf16(a[mi], b[ni], acc[mi][ni], 0, 0, 0);
        __builtin_amdgcn_s_setprio(0);
        if (kt+2 < 32) { WAIT_VM4; } else { WAIT_VM0; }
        BARRIER;
    }
    #undef STAGE_P
    #pragma unroll
    for (int mi = 0; mi < 4; ++mi)
        #pragma unroll
        for (int ni = 0; ni < 4; ++ni)
            #pragma unroll
            for (int r = 0; r < 4; ++r) {
                int row = m0 + wm*64 + mi*16 + (lane>>4)*4 + r;
                int col = n0 + wn*64 + ni*16 + (lane&15);
                float v = (acc[mi][ni][r] + bias[col]) * scale;
                int bb = row >> 11, l = row & (Lc-1);
                int hh = col >> 6,  hd = col & 63;
                dst[(((size_t)bb*Hc + hh)*Lc + l)*128 + half*64 + hd] = (__bf16)v;
            }
}

// ---------------------------------------------------------------------------
// vt: VT[bh][d 0..63][l 0..2047] = Kc[bh][l][d]
// ---------------------------------------------------------------------------
__global__ __launch_bounds__(256) void vt_kernel(
    const __bf16* __restrict__ Kc, __bf16* __restrict__ VT)
{
    const int l0 = blockIdx.x * 128, hb = blockIdx.y;
    const int t = threadIdx.x, w = t >> 6, lane = t & 63;
    __shared__ __bf16 T[128][72];
    const __bf16* src = Kc + ((size_t)hb*Lc + l0)*128;
    {
        const int lr = t >> 3, cc = t & 7;
        #pragma unroll
        for (int j = 0; j < 4; ++j)
            *(bf16x8*)&T[lr + j*32][cc*8] = *(const bf16x8*)(src + (size_t)(lr + j*32)*128 + cc*8);
    }
    __syncthreads();
    {
        const int d = lane;
        __bf16* dstp = VT + ((size_t)hb*64 + d)*Lc + l0 + w*32;
        #pragma unroll
        for (int j = 0; j < 4; ++j) {
            bf16x8 o;
            #pragma unroll
            for (int i = 0; i < 8; ++i) o[i] = T[w*32 + j*8 + i][d];
            *(bf16x8*)(dstp + j*8) = o;
        }
    }
}

// ---------------------------------------------------------------------------
// attn1: lsum pass (r11 body, unchanged).
// ---------------------------------------------------------------------------
__global__ __launch_bounds__(256, 3) void attn1_kernel(
    const __bf16* __restrict__ Qc, const __bf16* __restrict__ Kc,
    const float* __restrict__ rel_bias, float* __restrict__ baddp)
{
    const int g = blockIdx.x;
    const int qt = g >> 5, hb = g & 31, h = hb & 15;
    const int q0 = qt * 128;
    const int t = threadIdx.x, lane = t & 63, w = t >> 6;
    const int ln31 = lane & 31, hi = lane >> 5;

    const __bf16* Qp = Qc + (size_t)hb * Lc * 128;
    const __bf16* Kp = Kc + (size_t)hb * Lc * 128;

    __shared__ __align__(16) char smem[49152];   // 3 x 16KB K buffers

    bf16x8 qa[8];
    {
        const __bf16* qrow = Qp + (size_t)(q0 + w*32 + ln31) * 128 + hi*8;
        #pragma unroll
        for (int ks = 0; ks < 8; ++ks) qa[ks] = *(const bf16x8*)(qrow + ks*16);
    }

    int kof[4];
    #pragma unroll
    for (int c = 0; c < 4; ++c) {
        int rl = c*4 + (lane >> 4);
        int rr = w*16 + rl;
        kof[c] = rr*128 + (((lane & 15) ^ rl) * 8);
    }
    int kR[8];
    #pragma unroll
    for (int ks = 0; ks < 8; ++ks) kR[ks] = ((ks*2 + hi) ^ (lane & 15)) * 8;

    #define STAGE_K(B, KT) do { \
        const __bf16* kb_ = Kp + (size_t)(KT)*8192; \
        gl_lds16(kb_ + kof[0], smem + ((B)*64 + w*16 +  0)*256); \
        gl_lds16(kb_ + kof[1], smem + ((B)*64 + w*16 +  4)*256); \
        gl_lds16(kb_ + kof[2], smem + ((B)*64 + w*16 +  8)*256); \
        gl_lds16(kb_ + kof[3], smem + ((B)*64 + w*16 + 12)*256); \
    } while (0)
    #define KB(B, ROW, KS) (*(const bf16x8*)(smem + ((B)*64 + (ROW))*256 + kR[KS]*2))

    const float bc = rel_bias[h] * 0.18033688011112042f;
    float lp[4] = {0.f, 0.f, 0.f, 0.f};

    STAGE_K(0, 0); STAGE_K(1, 1);
    WAIT_VM4; BARRIER;
    for (int kt = 0; kt < NT; ++kt) {
        if (kt+2 < NT) STAGE_K((kt+2) % 3, kt+2);
        SBAR;
        const int buf = kt % 3;
        f32x16 s0, s1;
        #pragma unroll
        for (int r = 0; r < 16; ++r) { s0[r] = bc; s1[r] = bc; }
        __builtin_amdgcn_s_setprio(1);
        #pragma unroll
        for (int ks = 0; ks < 8; ++ks) {
            bf16x8 kb0 = KB(buf, ln31, ks);
            bf16x8 kb1 = KB(buf, 32 + ln31, ks);
            s0 = __builtin_amdgcn_mfma_f32_32x32x16_bf16(kb0, qa[ks], s0, 0, 0, 0);
            s1 = __builtin_amdgcn_mfma_f32_32x32x16_bf16(kb1, qa[ks], s1, 0, 0, 0);
        }
        __builtin_amdgcn_s_setprio(0);
        #pragma unroll
        for (int r = 0; r < 16; ++r) {
            lp[r & 3] += E2(s0[r]);
            lp[r & 3] += E2(s1[r]);
        }
        if (kt+2 < NT) { WAIT_VM4; } else { WAIT_VM0; }
        BARRIER;
    }
    float lsum = (lp[0] + lp[1]) + (lp[2] + lp[3]);
    lsum += __shfl_xor(lsum, 32);
    if (!hi) baddp[(size_t)hb*Lc + q0 + w*32 + ln31] = bc - log2f(lsum);
    #undef STAGE_K
    #undef KB
}

// ---------------------------------------------------------------------------
// attn2: P out + PV (r11 body, unchanged).
// ---------------------------------------------------------------------------
__global__ __launch_bounds__(256, 2) void attn2_kernel(
    const __bf16* __restrict__ Qc, const __bf16* __restrict__ Kc,
    const __bf16* __restrict__ VT, const float* __restrict__ baddp,
    float* __restrict__ attn, __bf16* __restrict__ ctxh)
{
    const int g = blockIdx.x;
    const int qt = g >> 5, hb = g & 31, h = hb & 15, bb = hb >> 4;
    const int q0 = qt * 128;
    const int t = threadIdx.x, lane = t & 63, w = t >> 6;
    const int ln31 = lane & 31, hi = lane >> 5;

    const __bf16* Qp = Qc + (size_t)hb * Lc * 128;
    const __bf16* Kp = Kc + (size_t)hb * Lc * 128;
    const __bf16* Vp = VT + (size_t)hb * 64 * Lc;

    // LDS: K 3x16KB @0 | V 2x8KB @49152 | Ps 4x4KB @65536 = 80KB
    __shared__ __align__(16) char smem[81920];
    char* const VsB = smem + 49152;
    char* const PsW = smem + 65536 + w*4096;

    bf16x8 qa[8];
    {
        const __bf16* qrow = Qp + (size_t)(q0 + w*32 + ln31) * 128 + hi*8;
        #pragma unroll
        for (int ks = 0; ks < 8; ++ks) qa[ks] = *(const bf16x8*)(qrow + ks*16);
    }
    const float badd = baddp[(size_t)hb*Lc + q0 + w*32 + ln31];

    int kof[4];
    #pragma unroll
    for (int c = 0; c < 4; ++c) {
        int rl = c*4 + (lane >> 4);
        int rr = w*16 + rl;
        kof[c] = rr*128 + (((lane & 15) ^ rl) * 8);
    }
    int vof[2];
    #pragma unroll
    for (int c = 0; c < 2; ++c) {
        int dl = lane >> 3;
        int dd = w*16 + c*8 + dl;
        vof[c] = dd*2048 + (((lane & 7) ^ dl) * 8);
    }
    int kR[8];
    #pragma unroll
    for (int ks = 0; ks < 8; ++ks) kR[ks] = ((ks*2 + hi) ^ (lane & 15)) * 8;
    int vR[4];
    #pragma unroll
    for (int ks = 0; ks < 4; ++ks) vR[ks] = ((ks*2 + hi) ^ (lane & 7)) * 8;

    #define STAGE_K(B, KT) do { \
        const __bf16* kb_ = Kp + (size_t)(KT)*8192; \
        gl_lds16(kb_ + kof[0], smem + ((B)*64 + w*16 +  0)*256); \
        gl_lds16(kb_ + kof[1], smem + ((B)*64 + w*16 +  4)*256); \
        gl_lds16(kb_ + kof[2], smem + ((B)*64 + w*16 +  8)*256); \
        gl_lds16(kb_ + kof[3], smem + ((B)*64 + w*16 + 12)*256); \
    } while (0)
    #define STAGE_V(B, KT) do { \
        const __bf16* vb_ = Vp + (KT)*64; \
        gl_lds16(vb_ + vof[0], VsB + ((B)*64 + w*16 + 0)*128); \
        gl_lds16(vb_ + vof[1], VsB + ((B)*64 + w*16 + 8)*128); \
    } while (0)
    #define KB(B, ROW, KS) (*(const bf16x8*)(smem + ((B)*64 + (ROW))*256 + kR[KS]*2))
    #define VB(B, ROW, KS) (*(const bf16x8*)(VsB  + ((B)*64 + (ROW))*128 + vR[KS]*2))

    f32x16 ctx0 = {}, ctx1 = {};
    float* abase = attn + ((size_t)hb*Lc + q0 + w*32)*Lc;
    const int rr2 = lane >> 4;
    const int s8  = lane & 15;

    STAGE_K(0, 0); STAGE_V(0, 0); STAGE_K(1, 1);
    WAIT_VM4; BARRIER;

    for (int kt = 0; kt < NT; ++kt) {
        if (kt+1 < NT) STAGE_V((kt+1) & 1, kt+1);
        if (kt+2 < NT) STAGE_K((kt+2) % 3, kt+2);
        SBAR;
        const int buf = kt % 3;
        f32x16 s0, s1;
        #pragma unroll
        for (int r = 0; r < 16; ++r) { s0[r] = badd; s1[r] = badd; }
        __builtin_amdgcn_s_setprio(1);
        #pragma unroll
        for (int ks = 0; ks < 8; ++ks) {
            bf16x8 kb0 = KB(buf, ln31, ks);
            bf16x8 kb1 = KB(buf, 32 + ln31, ks);
            s0 = __builtin_amdgcn_mfma_f32_32x32x16_bf16(kb0, qa[ks], s0, 0, 0, 0);
            s1 = __builtin_amdgcn_mfma_f32_32x32x16_bf16(kb1, qa[ks], s1, 0, 0, 0);
        }
        __builtin_amdgcn_s_setprio(0);
        unsigned u0[8], u1[8], r0[8], r1[8];
        #pragma unroll
        for (int gq = 0; gq < 4; ++gq) {
            u0[gq]   = pkbf(E2(s0[4*gq+0]), E2(s0[4*gq+1]));
            u1[gq]   = pkbf(E2(s0[4*gq+2]), E2(s0[4*gq+3]));
            u0[4+gq] = pkbf(E2(s1[4*gq+0]), E2(s1[4*gq+1]));
            u1[4+gq] = pkbf(E2(s1[4*gq+2]), E2(s1[4*gq+3]));
        }
        #pragma unroll
        for (int gq = 0; gq < 8; ++gq) {
            r0[gq] = __shfl_xor(u0[gq], 32);
            r1[gq] = __shfl_xor(u1[gq], 32);
        }
        bf16x8 pb[4];
        #pragma unroll
        for (int ks = 0; ks < 4; ++ks) {
            const int gq = 2*ks + hi;
            U4 u;
            u.u[0] = hi ? r0[gq] : u0[gq];
            u.u[1] = hi ? r1[gq] : u1[gq];
            u.u[2] = hi ? u0[gq] : r0[gq];
            u.u[3] = hi ? u1[gq] : r1[gq];
            pb[ks] = u.v;
            *(bf16x8*)(PsW + ln31*128 + ((gq ^ (ln31 & 7))*16)) = u.v;
        }
        __builtin_amdgcn_s_setprio(1);
        #pragma unroll
        for (int ks = 0; ks < 4; ++ks) {
            bf16x8 v0 = VB(kt & 1, ln31, ks);
            bf16x8 v1 = VB(kt & 1, 32 + ln31, ks);
            ctx0 = __builtin_amdgcn_mfma_f32_32x32x16_bf16(pb[ks], v0, ctx0, 0, 0, 0);
            ctx1 = __builtin_amdgcn_mfma_f32_32x32x16_bf16(pb[ks], v1, ctx1, 0, 0, 0);
        }
        __builtin_amdgcn_s_setprio(0);
        WAIT_LG0; SBAR;
        #pragma unroll
        for (int j = 0; j < 8; ++j) {
            const int row = j*4 + rr2;
            u32x2 d = *(const u32x2*)(PsW + row*128 + (((s8>>1) ^ (row&7))*16) + (s8&1)*8);
            f32x4 o;
            o[0]=lo2f(d[0]); o[1]=hi2f(d[0]); o[2]=lo2f(d[1]); o[3]=hi2f(d[1]);
            __builtin_nontemporal_store(o, (f32x4*)(abase + (size_t)row*Lc + kt*64 + s8*4));
        }
        if (kt+1 < NT) {
            if (kt+2 < NT) { WAIT_VM12; } else { WAIT_VM8; }
            BARRIER;
        }
    }

    #pragma unroll
    for (int r = 0; r < 16; ++r) {
        const int R = (r&3) + 8*(r>>2) + 4*hi;
        const size_t row = (size_t)bb*Lc + q0 + w*32 + R;
        ctxh[row*Dc + h*64 + ln31]      = (__bf16)ctx0[r];
        ctxh[row*Dc + h*64 + 32 + ln31] = (__bf16)ctx1[r];
    }
    #undef STAGE_K
    #undef STAGE_V
    #undef KB
    #undef VB
}

// ---------------------------------------------------------------------------
// out: ctxh(bf16) @ Wo + bo, B split hi/lo. 3-buffer counted-vmcnt pipeline.
// ---------------------------------------------------------------------------
__global__ __launch_bounds__(256) void out_kernel(
    const __bf16* __restrict__ ctxh, const __bf16* __restrict__ Woh,
    const __bf16* __restrict__ Wol, const float* __restrict__ bo,
    float* __restrict__ out)
{
    const int m0 = blockIdx.y * 128, n0 = blockIdx.x * 128;
    const int t = threadIdx.x, lane = t & 63, w = t >> 6;
    const int wm = w >> 1, wn = w & 1;

    __shared__ __align__(16) char smem[73728];   // 3 x (A 8KB | Bh 8KB | Bl 8KB)

    const int row4 = lane >> 2;
    const int scol = ((lane & 3) ^ (row4 & 3)) * 8;

    f32x4 acc[4][4] = {};

    #define STAGE_O(B, KT) do { \
        const int k0_ = (KT)*32; \
        _Pragma("unroll") \
        for (int i = 0; i < 2; ++i) { \
            int row = 16*(2*w+i) + row4; \
            gl_lds16(ctxh + (size_t)(m0+row)*Dc + k0_ + scol, smem + (B)*24576 + (2*w+i)*1024); \
            gl_lds16(Woh  + (size_t)(n0+row)*Dc + k0_ + scol, smem + (B)*24576 + 8192 + (2*w+i)*1024); \
            gl_lds16(Wol  + (size_t)(n0+row)*Dc + k0_ + scol, smem + (B)*24576 + 16384 + (2*w+i)*1024); \
        } \
    } while (0)

    STAGE_O(0, 0); STAGE_O(1, 1);
    WAIT_VM6; BARRIER;
    for (int kt = 0; kt < 32; ++kt) {
        if (kt+2 < 32) STAGE_O((kt+2) % 3, kt+2);
        SBAR;
        const int buf = kt % 3;
        bf16x8 a[4], bh[4], bl[4];
        const int s2 = lane >> 4;
        #pragma unroll
        for (int i = 0; i < 4; ++i) {
            int Ra = wm*64 + i*16 + (lane&15);
            int Rb = wn*64 + i*16 + (lane&15);
            a[i]  = *(const bf16x8*)(smem + buf*24576 + Ra*64 + ((s2 ^ (Ra&3))*16));
            bh[i] = *(const bf16x8*)(smem + buf*24576 + 8192 + Rb*64 + ((s2 ^ (Rb&3))*16));
            bl[i] = *(const bf16x8*)(smem + buf*24576 + 16384 + Rb*64 + ((s2 ^ (Rb&3))*16));
        }
        __builtin_amdgcn_s_setprio(1);
        #pragma unroll
        for (int mi = 0; mi < 4; ++mi)
            #pragma unroll
            for (int ni = 0; ni < 4; ++ni) {
                acc[mi][ni] = __builtin_amdgcn_mfma_f32_16x16x32_bf16(a[mi], bh[ni], acc[mi][ni], 0, 0, 0);
                acc[mi][ni] = __builtin_amdgcn_mfma_f32_16x16x32_bf16(a[mi], bl[ni], acc[mi][ni], 0, 0, 0);
            }
        __builtin_amdgcn_s_setprio(0);
        if (kt+2 < 32) { WAIT_VM6; } else { WAIT_VM0; }
        BARRIER;
    }
    #undef STAGE_O
    #pragma unroll
    for (int mi = 0; mi < 4; ++mi)
        #pragma unroll
        for (int ni = 0; ni < 4; ++ni)
            #pragma unroll
            for (int r = 0; r < 4; ++r) {
                int row = m0 + wm*64 + mi*16 + (lane>>4)*4 + r;
                int col = n0 + wn*64 + ni*16 + (lane&15);
                __builtin_nontemporal_store(acc[mi][ni][r] + bo[col],
                                            out + (size_t)row * Dc + col);
            }
}

// ---------------------------------------------------------------------------
extern "C" void kernel_launch(void* const* d_in, const int* in_sizes, int n_in,
                              void* d_out, int out_size, void* d_ws, size_t ws_size,
                              hipStream_t stream)
{
    const float* hidden = (const float*)d_in[0];
    const float* pos    = (const float*)d_in[1];
    const float* Wcq = (const float*)d_in[2];  const float* bcq = (const float*)d_in[3];
    const float* Wck = (const float*)d_in[4];  const float* bck = (const float*)d_in[5];
    const float* Wpq = (const float*)d_in[6];  const float* bpq = (const float*)d_in[7];
    const float* Wpk = (const float*)d_in[8];  const float* bpk = (const float*)d_in[9];
    const float* relb = (const float*)d_in[10];
    const float* Wo  = (const float*)d_in[11]; const float* bo  = (const float*)d_in[12];

    float* out  = (float*)d_out;
    float* attn = out + (size_t)Mc * Dc;

    // ws (bf16 elems): Woh[0,1M) Wol[1M,2M) Wt[2M,6M) (ctxh overlays Wt)
    // Qc[6M,14M) Kc[14M,22M) VT[22M,26M) badd f32 @26M
    __bf16* ws   = (__bf16*)d_ws;
    __bf16* Woh  = ws;
    __bf16* Wol  = ws + (1u<<20);
    __bf16* Wt   = ws + (2u<<20);
    __bf16* ctxh = Wt;
    __bf16* Qc   = ws + (6u<<20);
    __bf16* Kc   = ws + (14u<<20);
    __bf16* VTb  = ws + (22u<<20);
    float*  badd = (float*)(ws + (26u<<20));

    // bf16 casts of hidden/pos live in the attn output region (16 MB of 512 MB);
    // consumed by proj, overwritten later by attn2's P stores.
    __bf16* Xh = (__bf16*)attn;
    __bf16* Xp = Xh + (4u<<20);

    prep_kernel<<<dim3(16, 8, 7), 256, 0, stream>>>(
        hidden, pos, Wcq, Wck, Wpq, Wpk, Wo, Wt, Woh, Wol, Xh, Xp);
    proj_kernel<<<dim3(1024), 256, 0, stream>>>(Xh, Xp, Wt, bcq, bck, bpq, bpk, Qc, Kc);
    vt_kernel<<<dim3(Lc/128, 32), 256, 0, stream>>>(Kc, VTb);
    attn1_kernel<<<dim3(512), 256, 0, stream>>>(Qc, Kc, relb, badd);
    attn2_kernel<<<dim3(512), 256, 0, stream>>>(Qc, Kc, VTb, badd, attn, ctxh);
    out_kernel<<<dim3(8, 32), 256, 0, stream>>>(ctxh, Woh, Wol, bo, out);
}

// Round 13
// 282.341 us; speedup vs baseline: 1.2671x; 1.0984x over previous
//
#include <hip/hip_runtime.h>
#include <hip/hip_bf16.h>
#include <math.h>

// RaffelAttention round 13 = r12 with attn1/attn2 widened to 256-q tiles
// (512 threads, 8 waves): halves staging ops + barriers per MFMA.
// vmcnt re-derived: attn1 steady vm2; attn2 steady vm10 (8 stores + 2 K).
// proj/out/prep/vt byte-identical to r12.

#define Bc 2
#define Lc 2048
#define Dc 1024
#define Hc 16
#define Mc (Bc*Lc)
#define NT 32

typedef __attribute__((ext_vector_type(8))) __bf16 bf16x8;
typedef __attribute__((ext_vector_type(4))) float f32x4;
typedef __attribute__((ext_vector_type(16))) float f32x16;
typedef __attribute__((ext_vector_type(2))) unsigned u32x2;

union U4 { unsigned u[4]; bf16x8 v; };

__device__ __forceinline__ void gl_lds16(const void* g, void* l) {
    __builtin_amdgcn_global_load_lds(
        (const __attribute__((address_space(1))) void*)g,
        (__attribute__((address_space(3))) void*)l, 16, 0, 0);
}
__device__ __forceinline__ unsigned pkbf(float a, float b) {
    unsigned short ua = __builtin_bit_cast(unsigned short, (__bf16)a);
    unsigned short ub = __builtin_bit_cast(unsigned short, (__bf16)b);
    return (unsigned)ua | ((unsigned)ub << 16);
}
__device__ __forceinline__ float lo2f(unsigned u){ return __builtin_bit_cast(float, u << 16); }
__device__ __forceinline__ float hi2f(unsigned u){ return __builtin_bit_cast(float, u & 0xffff0000u); }
#define E2(x) __builtin_amdgcn_exp2f(x)

#define WAIT_VM0  asm volatile("s_waitcnt vmcnt(0)" ::: "memory")
#define WAIT_VM2  asm volatile("s_waitcnt vmcnt(2)" ::: "memory")
#define WAIT_VM4  asm volatile("s_waitcnt vmcnt(4)" ::: "memory")
#define WAIT_VM6  asm volatile("s_waitcnt vmcnt(6)" ::: "memory")
#define WAIT_VM8  asm volatile("s_waitcnt vmcnt(8)" ::: "memory")
#define WAIT_VM10 asm volatile("s_waitcnt vmcnt(10)" ::: "memory")
#define WAIT_LG0  asm volatile("s_waitcnt lgkmcnt(0)" ::: "memory")
#define SBAR __builtin_amdgcn_sched_barrier(0)
#define BARRIER do { __builtin_amdgcn_sched_barrier(0); __builtin_amdgcn_s_barrier(); __builtin_amdgcn_sched_barrier(0); } while (0)

// ---------------------------------------------------------------------------
// prep: z=0..3 Wt[z] bf16 [n][k]; z=4 Woh/Wol; z=5,6 cast hidden/pos to bf16.
// ---------------------------------------------------------------------------
__global__ __launch_bounds__(256) void prep_kernel(
    const float* __restrict__ hidden, const float* __restrict__ pos,
    const float* __restrict__ Wcq, const float* __restrict__ Wck,
    const float* __restrict__ Wpq, const float* __restrict__ Wpk,
    const float* __restrict__ Wo,
    __bf16* __restrict__ Wt, __bf16* __restrict__ Woh, __bf16* __restrict__ Wol,
    __bf16* __restrict__ Xh, __bf16* __restrict__ Xp)
{
    const int z = blockIdx.z;
    const int t = threadIdx.x;
    if (z >= 5) {   // straight cast
        const float* X = (z==5) ? hidden : pos;
        __bf16* dst    = (z==5) ? Xh : Xp;
        const size_t base = ((size_t)(blockIdx.y*16 + blockIdx.x)*256 + t) * 128;
        #pragma unroll
        for (int c = 0; c < 16; ++c) {
            const float* sp = X + base + c*8;
            float4 v0 = *(const float4*)sp;
            float4 v1 = *(const float4*)(sp + 4);
            bf16x8 o;
            o[0]=(__bf16)v0.x; o[1]=(__bf16)v0.y; o[2]=(__bf16)v0.z; o[3]=(__bf16)v0.w;
            o[4]=(__bf16)v1.x; o[5]=(__bf16)v1.y; o[6]=(__bf16)v1.z; o[7]=(__bf16)v1.w;
            *(bf16x8*)(dst + base + c*8) = o;
        }
        return;
    }
    const float* W = (z==0)?Wcq:(z==1)?Wck:(z==2)?Wpq:(z==3)?Wpk:Wo;
    const int n  = blockIdx.x*64 + (t & 63);
    const int k0 = blockIdx.y*128 + (t >> 6)*32;
    float v[32];
    #pragma unroll
    for (int j = 0; j < 32; ++j) v[j] = W[(size_t)(k0+j)*Dc + n];
    if (z < 4) {
        __bf16* dst = Wt + (size_t)z*Dc*Dc + (size_t)n*Dc + k0;
        #pragma unroll
        for (int c = 0; c < 4; ++c) {
            bf16x8 o;
            #pragma unroll
            for (int j = 0; j < 8; ++j) o[j] = (__bf16)v[c*8+j];
            *(bf16x8*)(dst + c*8) = o;
        }
    } else {
        __bf16* dh = Woh + (size_t)n*Dc + k0;
        __bf16* dl = Wol + (size_t)n*Dc + k0;
        #pragma unroll
        for (int c = 0; c < 4; ++c) {
            bf16x8 oh, ol;
            #pragma unroll
            for (int j = 0; j < 8; ++j) {
                float x = v[c*8+j];
                __bf16 hi = (__bf16)x;
                oh[j] = hi; ol[j] = (__bf16)(x - (float)hi);
            }
            *(bf16x8*)(dh + c*8) = oh;
            *(bf16x8*)(dl + c*8) = ol;
        }
    }
}

// ---------------------------------------------------------------------------
// proj: X(bf16) @ Wt[z](bf16,[n][k]) -> Q'/K'. BK=32, 3-buffer pipeline (r12).
// ---------------------------------------------------------------------------
__global__ __launch_bounds__(256) void proj_kernel(
    const __bf16* __restrict__ Xh, const __bf16* __restrict__ Xp,
    const __bf16* __restrict__ Wt,
    const float* __restrict__ bcq, const float* __restrict__ bck,
    const float* __restrict__ bpq, const float* __restrict__ bpk,
    __bf16* __restrict__ Qc, __bf16* __restrict__ Kc)
{
    const int g = blockIdx.x;
    const int nblk = g >> 7, sg = g & 127, mblk = sg & 31, z = sg >> 5;
    const int m0 = mblk*128, n0 = nblk*128;
    const __bf16* X = (z < 2) ? Xh : Xp;
    const __bf16* Wz = Wt + (size_t)z*Dc*Dc;
    const float* bias = (z==0)?bcq:(z==1)?bck:(z==2)?bpq:bpk;
    __bf16* dst = (z & 1) ? Kc : Qc;
    const int half = z >> 1;
    const float scale = (z & 1) ? 1.0f : 0.18033688011112042f; // 0.125*log2e on Q

    const int t = threadIdx.x, lane = t & 63, w = t >> 6;
    const int wm = w >> 1, wn = w & 1;

    __shared__ __align__(16) char smem[49152];   // 3 x (A 8KB | B 8KB)

    const int brow4 = lane >> 2;                       // 0..15
    const int bcol  = ((lane & 3) ^ (brow4 & 3)) * 8;  // bf16 col, swizzled

    f32x4 acc[4][4] = {};

    #define STAGE_P(B, KT) do { \
        const int k0_ = (KT)*32; \
        _Pragma("unroll") \
        for (int i = 0; i < 2; ++i) { \
            int row = 16*(2*w+i) + brow4; \
            gl_lds16(X  + (size_t)(m0+row)*Dc + k0_ + bcol, smem + (B)*16384 + (2*w+i)*1024); \
            gl_lds16(Wz + (size_t)(n0+row)*Dc + k0_ + bcol, smem + (B)*16384 + 8192 + (2*w+i)*1024); \
        } \
    } while (0)

    STAGE_P(0, 0); STAGE_P(1, 1);
    WAIT_VM4; BARRIER;
    for (int kt = 0; kt < 32; ++kt) {
        if (kt+2 < 32) STAGE_P((kt+2) % 3, kt+2);
        SBAR;
        const int buf = kt % 3;
        bf16x8 a[4], b[4];
        const int s2 = lane >> 4;
        #pragma unroll
        for (int i = 0; i < 4; ++i) {
            int Ra = wm*64 + i*16 + (lane&15);
            int Rb = wn*64 + i*16 + (lane&15);
            a[i] = *(const bf16x8*)(smem + buf*16384 + Ra*64 + ((s2 ^ (Ra&3))*16));
            b[i] = *(const bf16x8*)(smem + buf*16384 + 8192 + Rb*64 + ((s2 ^ (Rb&3))*16));
        }
        __builtin_amdgcn_s_setprio(1);
        #pragma unroll
        for (int mi = 0; mi < 4; ++mi)
            #pragma unroll
            for (int ni = 0; ni < 4; ++ni)
                acc[mi][ni] = __builtin_amdgcn_mfma_f32_16x16x32_bf16(a[mi], b[ni], acc[mi][ni], 0, 0, 0);
        __builtin_amdgcn_s_setprio(0);
        if (kt+2 < 32) { WAIT_VM4; } else { WAIT_VM0; }
        BARRIER;
    }
    #undef STAGE_P
    #pragma unroll
    for (int mi = 0; mi < 4; ++mi)
        #pragma unroll
        for (int ni = 0; ni < 4; ++ni)
            #pragma unroll
            for (int r = 0; r < 4; ++r) {
                int row = m0 + wm*64 + mi*16 + (lane>>4)*4 + r;
                int col = n0 + wn*64 + ni*16 + (lane&15);
                float v = (acc[mi][ni][r] + bias[col]) * scale;
                int bb = row >> 11, l = row & (Lc-1);
                int hh = col >> 6,  hd = col & 63;
                dst[(((size_t)bb*Hc + hh)*Lc + l)*128 + half*64 + hd] = (__bf16)v;
            }
}

// ---------------------------------------------------------------------------
// vt: VT[bh][d 0..63][l 0..2047] = Kc[bh][l][d]
// ---------------------------------------------------------------------------
__global__ __launch_bounds__(256) void vt_kernel(
    const __bf16* __restrict__ Kc, __bf16* __restrict__ VT)
{
    const int l0 = blockIdx.x * 128, hb = blockIdx.y;
    const int t = threadIdx.x, w = t >> 6, lane = t & 63;
    __shared__ __bf16 T[128][72];
    const __bf16* src = Kc + ((size_t)hb*Lc + l0)*128;
    {
        const int lr = t >> 3, cc = t & 7;
        #pragma unroll
        for (int j = 0; j < 4; ++j)
            *(bf16x8*)&T[lr + j*32][cc*8] = *(const bf16x8*)(src + (size_t)(lr + j*32)*128 + cc*8);
    }
    __syncthreads();
    {
        const int d = lane;
        __bf16* dstp = VT + ((size_t)hb*64 + d)*Lc + l0 + w*32;
        #pragma unroll
        for (int j = 0; j < 4; ++j) {
            bf16x8 o;
            #pragma unroll
            for (int i = 0; i < 8; ++i) o[i] = T[w*32 + j*8 + i][d];
            *(bf16x8*)(dstp + j*8) = o;
        }
    }
}

// ---------------------------------------------------------------------------
// attn1: lsum pass. 256-q tiles, 8 waves. 3-buf K, steady vmcnt(2).
// ---------------------------------------------------------------------------
__global__ __launch_bounds__(512, 4) void attn1_kernel(
    const __bf16* __restrict__ Qc, const __bf16* __restrict__ Kc,
    const float* __restrict__ rel_bias, float* __restrict__ baddp)
{
    const int g = blockIdx.x;
    const int qt = g >> 5, hb = g & 31, h = hb & 15;
    const int q0 = qt * 256;
    const int t = threadIdx.x, lane = t & 63, w = t >> 6;
    const int ln31 = lane & 31, hi = lane >> 5;

    const __bf16* Qp = Qc + (size_t)hb * Lc * 128;
    const __bf16* Kp = Kc + (size_t)hb * Lc * 128;

    __shared__ __align__(16) char smem[49152];   // 3 x 16KB K buffers

    bf16x8 qa[8];
    {
        const __bf16* qrow = Qp + (size_t)(q0 + w*32 + ln31) * 128 + hi*8;
        #pragma unroll
        for (int ks = 0; ks < 8; ++ks) qa[ks] = *(const bf16x8*)(qrow + ks*16);
    }

    // per-wave: 2 gl_lds, rows w*8 + c*4 + (lane>>4)
    int kof[2];
    #pragma unroll
    for (int c = 0; c < 2; ++c) {
        int rr = w*8 + c*4 + (lane >> 4);
        kof[c] = rr*128 + (((lane & 15) ^ (rr & 15)) * 8);
    }
    int kR[8];
    #pragma unroll
    for (int ks = 0; ks < 8; ++ks) kR[ks] = ((ks*2 + hi) ^ (lane & 15)) * 8;

    #define STAGE_K(B, KT) do { \
        const __bf16* kb_ = Kp + (size_t)(KT)*8192; \
        gl_lds16(kb_ + kof[0], smem + (B)*16384 + (w*8 + 0)*256); \
        gl_lds16(kb_ + kof[1], smem + (B)*16384 + (w*8 + 4)*256); \
    } while (0)
    #define KB(B, ROW, KS) (*(const bf16x8*)(smem + (B)*16384 + (ROW)*256 + kR[KS]*2))

    const float bc = rel_bias[h] * 0.18033688011112042f;
    float lp[4] = {0.f, 0.f, 0.f, 0.f};

    STAGE_K(0, 0); STAGE_K(1, 1);
    WAIT_VM2; BARRIER;
    for (int kt = 0; kt < NT; ++kt) {
        if (kt+2 < NT) STAGE_K((kt+2) % 3, kt+2);
        SBAR;
        const int buf = kt % 3;
        f32x16 s0, s1;
        #pragma unroll
        for (int r = 0; r < 16; ++r) { s0[r] = bc; s1[r] = bc; }
        __builtin_amdgcn_s_setprio(1);
        #pragma unroll
        for (int ks = 0; ks < 8; ++ks) {
            bf16x8 kb0 = KB(buf, ln31, ks);
            bf16x8 kb1 = KB(buf, 32 + ln31, ks);
            s0 = __builtin_amdgcn_mfma_f32_32x32x16_bf16(kb0, qa[ks], s0, 0, 0, 0);
            s1 = __builtin_amdgcn_mfma_f32_32x32x16_bf16(kb1, qa[ks], s1, 0, 0, 0);
        }
        __builtin_amdgcn_s_setprio(0);
        #pragma unroll
        for (int r = 0; r < 16; ++r) {
            lp[r & 3] += E2(s0[r]);
            lp[r & 3] += E2(s1[r]);
        }
        if (kt+2 < NT) { WAIT_VM2; } else { WAIT_VM0; }
        BARRIER;
    }
    float lsum = (lp[0] + lp[1]) + (lp[2] + lp[3]);
    lsum += __shfl_xor(lsum, 32);
    if (!hi) baddp[(size_t)hb*Lc + q0 + w*32 + ln31] = bc - log2f(lsum);
    #undef STAGE_K
    #undef KB
}

// ---------------------------------------------------------------------------
// attn2: P out + PV. 256-q tiles, 8 waves. K 3-buf / V 2-buf, steady vmcnt(10).
// ---------------------------------------------------------------------------
__global__ __launch_bounds__(512, 2) void attn2_kernel(
    const __bf16* __restrict__ Qc, const __bf16* __restrict__ Kc,
    const __bf16* __restrict__ VT, const float* __restrict__ baddp,
    float* __restrict__ attn, __bf16* __restrict__ ctxh)
{
    const int g = blockIdx.x;
    const int qt = g >> 5, hb = g & 31, h = hb & 15, bb = hb >> 4;
    const int q0 = qt * 256;
    const int t = threadIdx.x, lane = t & 63, w = t >> 6;
    const int ln31 = lane & 31, hi = lane >> 5;

    const __bf16* Qp = Qc + (size_t)hb * Lc * 128;
    const __bf16* Kp = Kc + (size_t)hb * Lc * 128;
    const __bf16* Vp = VT + (size_t)hb * 64 * Lc;

    // LDS: K 3x16KB @0 | V 2x8KB @49152 | Ps 8x4KB @65536 = 96KB
    __shared__ __align__(16) char smem[98304];
    char* const VsB = smem + 49152;
    char* const PsW = smem + 65536 + w*4096;

    bf16x8 qa[8];
    {
        const __bf16* qrow = Qp + (size_t)(q0 + w*32 + ln31) * 128 + hi*8;
        #pragma unroll
        for (int ks = 0; ks < 8; ++ks) qa[ks] = *(const bf16x8*)(qrow + ks*16);
    }
    const float badd = baddp[(size_t)hb*Lc + q0 + w*32 + ln31];

    int kof[2];
    #pragma unroll
    for (int c = 0; c < 2; ++c) {
        int rr = w*8 + c*4 + (lane >> 4);
        kof[c] = rr*128 + (((lane & 15) ^ (rr & 15)) * 8);
    }
    int vof;
    {
        int dl = lane >> 3;
        int dd = w*8 + dl;
        vof = dd*2048 + (((lane & 7) ^ dl) * 8);
    }
    int kR[8];
    #pragma unroll
    for (int ks = 0; ks < 8; ++ks) kR[ks] = ((ks*2 + hi) ^ (lane & 15)) * 8;
    int vR[4];
    #pragma unroll
    for (int ks = 0; ks < 4; ++ks) vR[ks] = ((ks*2 + hi) ^ (lane & 7)) * 8;

    #define STAGE_K(B, KT) do { \
        const __bf16* kb_ = Kp + (size_t)(KT)*8192; \
        gl_lds16(kb_ + kof[0], smem + (B)*16384 + (w*8 + 0)*256); \
        gl_lds16(kb_ + kof[1], smem + (B)*16384 + (w*8 + 4)*256); \
    } while (0)
    #define STAGE_V(B, KT) do { \
        const __bf16* vb_ = Vp + (KT)*64; \
        gl_lds16(vb_ + vof, VsB + (B)*8192 + (w*8)*128); \
    } while (0)
    #define KB(B, ROW, KS) (*(const bf16x8*)(smem + (B)*16384 + (ROW)*256 + kR[KS]*2))
    #define VB(B, ROW, KS) (*(const bf16x8*)(VsB  + (B)*8192 + (ROW)*128 + vR[KS]*2))

    f32x16 ctx0 = {}, ctx1 = {};
    float* abase = attn + ((size_t)hb*Lc + q0 + w*32)*Lc;
    const int rr2 = lane >> 4;
    const int s8  = lane & 15;

    STAGE_K(0, 0); STAGE_V(0, 0); STAGE_K(1, 1);
    WAIT_VM2; BARRIER;

    for (int kt = 0; kt < NT; ++kt) {
        if (kt+1 < NT) STAGE_V((kt+1) & 1, kt+1);     // 1 op (drained by wait)
        if (kt+2 < NT) STAGE_K((kt+2) % 3, kt+2);     // 2 ops (stay in flight)
        SBAR;
        const int buf = kt % 3;
        f32x16 s0, s1;
        #pragma unroll
        for (int r = 0; r < 16; ++r) { s0[r] = badd; s1[r] = badd; }
        __builtin_amdgcn_s_setprio(1);
        #pragma unroll
        for (int ks = 0; ks < 8; ++ks) {
            bf16x8 kb0 = KB(buf, ln31, ks);
            bf16x8 kb1 = KB(buf, 32 + ln31, ks);
            s0 = __builtin_amdgcn_mfma_f32_32x32x16_bf16(kb0, qa[ks], s0, 0, 0, 0);
            s1 = __builtin_amdgcn_mfma_f32_32x32x16_bf16(kb1, qa[ks], s1, 0, 0, 0);
        }
        __builtin_amdgcn_s_setprio(0);
        unsigned u0[8], u1[8], r0[8], r1[8];
        #pragma unroll
        for (int gq = 0; gq < 4; ++gq) {
            u0[gq]   = pkbf(E2(s0[4*gq+0]), E2(s0[4*gq+1]));
            u1[gq]   = pkbf(E2(s0[4*gq+2]), E2(s0[4*gq+3]));
            u0[4+gq] = pkbf(E2(s1[4*gq+0]), E2(s1[4*gq+1]));
            u1[4+gq] = pkbf(E2(s1[4*gq+2]), E2(s1[4*gq+3]));
        }
        #pragma unroll
        for (int gq = 0; gq < 8; ++gq) {
            r0[gq] = __shfl_xor(u0[gq], 32);
            r1[gq] = __shfl_xor(u1[gq], 32);
        }
        bf16x8 pb[4];
        #pragma unroll
        for (int ks = 0; ks < 4; ++ks) {
            const int gq = 2*ks + hi;
            U4 u;
            u.u[0] = hi ? r0[gq] : u0[gq];
            u.u[1] = hi ? r1[gq] : u1[gq];
            u.u[2] = hi ? u0[gq] : r0[gq];
            u.u[3] = hi ? u1[gq] : r1[gq];
            pb[ks] = u.v;
            *(bf16x8*)(PsW + ln31*128 + ((gq ^ (ln31 & 7))*16)) = u.v;
        }
        __builtin_amdgcn_s_setprio(1);
        #pragma unroll
        for (int ks = 0; ks < 4; ++ks) {
            bf16x8 v0 = VB(kt & 1, ln31, ks);
            bf16x8 v1 = VB(kt & 1, 32 + ln31, ks);
            ctx0 = __builtin_amdgcn_mfma_f32_32x32x16_bf16(pb[ks], v0, ctx0, 0, 0, 0);
            ctx1 = __builtin_amdgcn_mfma_f32_32x32x16_bf16(pb[ks], v1, ctx1, 0, 0, 0);
        }
        __builtin_amdgcn_s_setprio(0);
        WAIT_LG0; SBAR;
        #pragma unroll
        for (int j = 0; j < 8; ++j) {
            const int row = j*4 + rr2;
            u32x2 d = *(const u32x2*)(PsW + row*128 + (((s8>>1) ^ (row&7))*16) + (s8&1)*8);
            f32x4 o;
            o[0]=lo2f(d[0]); o[1]=hi2f(d[0]); o[2]=lo2f(d[1]); o[3]=hi2f(d[1]);
            __builtin_nontemporal_store(o, (f32x4*)(abase + (size_t)row*Lc + kt*64 + s8*4));
        }
        if (kt+1 < NT) {
            // keep 8 stores (+2 K(kt+2) if staged) in flight; drain V(kt+1)/K(kt+1)
            if (kt+2 < NT) { WAIT_VM10; } else { WAIT_VM8; }
            BARRIER;
        }
    }

    #pragma unroll
    for (int r = 0; r < 16; ++r) {
        const int R = (r&3) + 8*(r>>2) + 4*hi;
        const size_t row = (size_t)bb*Lc + q0 + w*32 + R;
        ctxh[row*Dc + h*64 + ln31]      = (__bf16)ctx0[r];
        ctxh[row*Dc + h*64 + 32 + ln31] = (__bf16)ctx1[r];
    }
    #undef STAGE_K
    #undef STAGE_V
    #undef KB
    #undef VB
}

// ---------------------------------------------------------------------------
// out: ctxh(bf16) @ Wo + bo, B split hi/lo. 3-buffer pipeline (r12).
// ---------------------------------------------------------------------------
__global__ __launch_bounds__(256) void out_kernel(
    const __bf16* __restrict__ ctxh, const __bf16* __restrict__ Woh,
    const __bf16* __restrict__ Wol, const float* __restrict__ bo,
    float* __restrict__ out)
{
    const int m0 = blockIdx.y * 128, n0 = blockIdx.x * 128;
    const int t = threadIdx.x, lane = t & 63, w = t >> 6;
    const int wm = w >> 1, wn = w & 1;

    __shared__ __align__(16) char smem[73728];   // 3 x (A 8KB | Bh 8KB | Bl 8KB)

    const int row4 = lane >> 2;
    const int scol = ((lane & 3) ^ (row4 & 3)) * 8;

    f32x4 acc[4][4] = {};

    #define STAGE_O(B, KT) do { \
        const int k0_ = (KT)*32; \
        _Pragma("unroll") \
        for (int i = 0; i < 2; ++i) { \
            int row = 16*(2*w+i) + row4; \
            gl_lds16(ctxh + (size_t)(m0+row)*Dc + k0_ + scol, smem + (B)*24576 + (2*w+i)*1024); \
            gl_lds16(Woh  + (size_t)(n0+row)*Dc + k0_ + scol, smem + (B)*24576 + 8192 + (2*w+i)*1024); \
            gl_lds16(Wol  + (size_t)(n0+row)*Dc + k0_ + scol, smem + (B)*24576 + 16384 + (2*w+i)*1024); \
        } \
    } while (0)

    STAGE_O(0, 0); STAGE_O(1, 1);
    WAIT_VM6; BARRIER;
    for (int kt = 0; kt < 32; ++kt) {
        if (kt+2 < 32) STAGE_O((kt+2) % 3, kt+2);
        SBAR;
        const int buf = kt % 3;
        bf16x8 a[4], bh[4], bl[4];
        const int s2 = lane >> 4;
        #pragma unroll
        for (int i = 0; i < 4; ++i) {
            int Ra = wm*64 + i*16 + (lane&15);
            int Rb = wn*64 + i*16 + (lane&15);
            a[i]  = *(const bf16x8*)(smem + buf*24576 + Ra*64 + ((s2 ^ (Ra&3))*16));
            bh[i] = *(const bf16x8*)(smem + buf*24576 + 8192 + Rb*64 + ((s2 ^ (Rb&3))*16));
            bl[i] = *(const bf16x8*)(smem + buf*24576 + 16384 + Rb*64 + ((s2 ^ (Rb&3))*16));
        }
        __builtin_amdgcn_s_setprio(1);
        #pragma unroll
        for (int mi = 0; mi < 4; ++mi)
            #pragma unroll
            for (int ni = 0; ni < 4; ++ni) {
                acc[mi][ni] = __builtin_amdgcn_mfma_f32_16x16x32_bf16(a[mi], bh[ni], acc[mi][ni], 0, 0, 0);
                acc[mi][ni] = __builtin_amdgcn_mfma_f32_16x16x32_bf16(a[mi], bl[ni], acc[mi][ni], 0, 0, 0);
            }
        __builtin_amdgcn_s_setprio(0);
        if (kt+2 < 32) { WAIT_VM6; } else { WAIT_VM0; }
        BARRIER;
    }
    #undef STAGE_O
    #pragma unroll
    for (int mi = 0; mi < 4; ++mi)
        #pragma unroll
        for (int ni = 0; ni < 4; ++ni)
            #pragma unroll
            for (int r = 0; r < 4; ++r) {
                int row = m0 + wm*64 + mi*16 + (lane>>4)*4 + r;
                int col = n0 + wn*64 + ni*16 + (lane&15);
                __builtin_nontemporal_store(acc[mi][ni][r] + bo[col],
                                            out + (size_t)row * Dc + col);
            }
}

// ---------------------------------------------------------------------------
extern "C" void kernel_launch(void* const* d_in, const int* in_sizes, int n_in,
                              void* d_out, int out_size, void* d_ws, size_t ws_size,
                              hipStream_t stream)
{
    const float* hidden = (const float*)d_in[0];
    const float* pos    = (const float*)d_in[1];
    const float* Wcq = (const float*)d_in[2];  const float* bcq = (const float*)d_in[3];
    const float* Wck = (const float*)d_in[4];  const float* bck = (const float*)d_in[5];
    const float* Wpq = (const float*)d_in[6];  const float* bpq = (const float*)d_in[7];
    const float* Wpk = (const float*)d_in[8];  const float* bpk = (const float*)d_in[9];
    const float* relb = (const float*)d_in[10];
    const float* Wo  = (const float*)d_in[11]; const float* bo  = (const float*)d_in[12];

    float* out  = (float*)d_out;
    float* attn = out + (size_t)Mc * Dc;

    // ws (bf16 elems): Woh[0,1M) Wol[1M,2M) Wt[2M,6M) (ctxh overlays Wt)
    // Qc[6M,14M) Kc[14M,22M) VT[22M,26M) badd f32 @26M
    __bf16* ws   = (__bf16*)d_ws;
    __bf16* Woh  = ws;
    __bf16* Wol  = ws + (1u<<20);
    __bf16* Wt   = ws + (2u<<20);
    __bf16* ctxh = Wt;
    __bf16* Qc   = ws + (6u<<20);
    __bf16* Kc   = ws + (14u<<20);
    __bf16* VTb  = ws + (22u<<20);
    float*  badd = (float*)(ws + (26u<<20));

    // bf16 casts of hidden/pos live in the attn output region (16 MB of 512 MB);
    // consumed by proj, overwritten later by attn2's P stores.
    __bf16* Xh = (__bf16*)attn;
    __bf16* Xp = Xh + (4u<<20);

    prep_kernel<<<dim3(16, 8, 7), 256, 0, stream>>>(
        hidden, pos, Wcq, Wck, Wpq, Wpk, Wo, Wt, Woh, Wol, Xh, Xp);
    proj_kernel<<<dim3(1024), 256, 0, stream>>>(Xh, Xp, Wt, bcq, bck, bpq, bpk, Qc, Kc);
    vt_kernel<<<dim3(Lc/128, 32), 256, 0, stream>>>(Kc, VTb);
    attn1_kernel<<<dim3(256), 512, 0, stream>>>(Qc, Kc, relb, badd);
    attn2_kernel<<<dim3(256), 512, 0, stream>>>(Qc, Kc, VTb, badd, attn, ctxh);
    out_kernel<<<dim3(8, 32), 256, 0, stream>>>(ctxh, Woh, Wol, bo, out);
}